// Round 13
// baseline (154.501 us; speedup 1.0000x reference)
//
#include <hip/hip_runtime.h>
#include <hip/hip_bf16.h>
#include <cstdint>

#define B_   2
#define NQ_  10000
#define C_   256
#define NH_  8
#define DH_  32
#define DFF_ 1024
#define S_   19560
#define MQ_P 20480   // 160*128 / 320*64 tiles; %8==0 -> stable row->XCD map
#define MV_P 39168   // 306*128

typedef __attribute__((ext_vector_type(8))) short short8;
typedef __attribute__((ext_vector_type(4))) float f32x4;
typedef __attribute__((ext_vector_type(2))) float f32x2;

__device__ __forceinline__ void gload16(const void* g, void* l) {
  __builtin_amdgcn_global_load_lds(
      (const __attribute__((address_space(1))) unsigned int*)g,
      (__attribute__((address_space(3))) unsigned int*)l, 16, 0, 0);
}

__device__ __forceinline__ float bflo(unsigned u) {
  union { unsigned u; float f; } c; c.u = u << 16; return c.f;
}
__device__ __forceinline__ float bfhi(unsigned u) {
  union { unsigned u; float f; } c; c.u = u & 0xffff0000u; return c.f;
}
__device__ __forceinline__ float bfhi_raw(unsigned u) {
  union { unsigned u; float f; } c; c.u = u; return c.f;
}

// ------------------------------------------------------------- prep (fused)
__global__ __launch_bounds__(256) void prep_all(
    const float* __restrict__ Wv, const float* __restrict__ Woff,
    const float* __restrict__ Wa, const float* __restrict__ Wo,
    const float* __restrict__ W1, const float* __restrict__ W2,
    __hip_bfloat16* __restrict__ wbase,
    const float* __restrict__ qf, const float* __restrict__ qp,
    __hip_bfloat16* __restrict__ q_bf) {
  __shared__ float tile[64][65];
  if (blockIdx.x < 184) {
    int blk = blockIdx.x;
    const float* W; __hip_bfloat16* Wt; int K, N;
    if (blk < 16)       { W = Wv;   Wt = wbase + 0;      K = 256;  N = 256; }
    else if (blk < 32)  { W = Woff; Wt = wbase + 65536;  K = 256;  N = 256;  blk -= 16; }
    else if (blk < 40)  { W = Wa;   Wt = wbase + 131072; K = 256;  N = 128;  blk -= 32; }
    else if (blk < 56)  { W = Wo;   Wt = wbase + 163840; K = 256;  N = 256;  blk -= 40; }
    else if (blk < 120) { W = W1;   Wt = wbase + 229376; K = 256;  N = 1024; blk -= 56; }
    else                { W = W2;   Wt = wbase + 491520; K = 1024; N = 256;  blk -= 120; }
    const int ntiles = N >> 6;
    const int kt = blk / ntiles, nt = blk % ntiles;
    const int c = threadIdx.x & 63, r0 = threadIdx.x >> 6;
#pragma unroll
    for (int i = 0; i < 16; ++i) {
      const int r = r0 + i * 4;
      tile[r][c] = W[(long)(kt * 64 + r) * N + nt * 64 + c];
    }
    __syncthreads();
#pragma unroll
    for (int i = 0; i < 16; ++i) {
      const int n = r0 + i * 4;
      Wt[(long)(nt * 64 + n) * K + kt * 64 + c] = __float2bfloat16(tile[c][n]);
    }
  } else {
    long idx = (long)(blockIdx.x - 184) * 256 + threadIdx.x;
    int row = idx >> 5, c8 = (idx & 31) * 8;
    union { __hip_bfloat16 h[8]; uint4 u; } o;
    if (row < B_ * NQ_) {
      const float4 a0 = *reinterpret_cast<const float4*>(qf + (long)row * 256 + c8);
      const float4 a1 = *reinterpret_cast<const float4*>(qf + (long)row * 256 + c8 + 4);
      const float4 b0 = *reinterpret_cast<const float4*>(qp + (long)row * 256 + c8);
      const float4 b1 = *reinterpret_cast<const float4*>(qp + (long)row * 256 + c8 + 4);
      o.h[0] = __float2bfloat16(a0.x + b0.x); o.h[1] = __float2bfloat16(a0.y + b0.y);
      o.h[2] = __float2bfloat16(a0.z + b0.z); o.h[3] = __float2bfloat16(a0.w + b0.w);
      o.h[4] = __float2bfloat16(a1.x + b1.x); o.h[5] = __float2bfloat16(a1.y + b1.y);
      o.h[6] = __float2bfloat16(a1.z + b1.z); o.h[7] = __float2bfloat16(a1.w + b1.w);
    } else o.u = make_uint4(0, 0, 0, 0);
    if (row < MQ_P) *reinterpret_cast<uint4*>(q_bf + (long)row * 256 + c8) = o.u;
  }
}

// ------------------------------------------------------------- MFMA GEMM 64x128
// Tile 64x128, BK=64, 256 thr (2x2 waves), XOR-swizzled LDS.
// MODE 2: bf16 out + ReLU. MODE 4: bf16 out.
template <int MODE>
__global__ __launch_bounds__(256) void gemm_bf16(
    const __hip_bfloat16* __restrict__ A, const __hip_bfloat16* __restrict__ Bt,
    const float* __restrict__ bias, const float* __restrict__ bias2, int bsplit,
    void* __restrict__ Cp, int M, int N, int K) {
  __shared__ short smA[64 * 64];    // 8KB
  __shared__ short smB[128 * 64];   // 16KB
  const int tid = threadIdx.x;
  const int lane = tid & 63;
  const int w = tid >> 6;
  const int wr = w >> 1, wc = w & 1;
  const long bm = (long)blockIdx.x * 64;
  const long bn = (long)blockIdx.y * 128;

  f32x4 acc[2][4];
#pragma unroll
  for (int i = 0; i < 2; ++i)
#pragma unroll
    for (int j = 0; j < 4; ++j) acc[i][j] = (f32x4)(0.f);

  const int srow = tid >> 3;
  const int su = (tid & 7) ^ (srow & 7);
  const __hip_bfloat16* Ag = A + (bm + srow) * (long)K + su * 8;
  const __hip_bfloat16* Bg = Bt + (bn + srow) * (long)K + su * 8;
  char* lA = (char*)smA + tid * 16;
  char* lB = (char*)smB + tid * 16;

  for (int k0 = 0; k0 < K; k0 += 64) {
    gload16(Ag,           lA);
    gload16(Ag + 32L * K, lA + 4096);
    gload16(Bg,           lB);
    gload16(Bg + 32L * K, lB + 4096);
    gload16(Bg + 64L * K, lB + 8192);
    gload16(Bg + 96L * K, lB + 12288);
    Ag += 64; Bg += 64;
    __syncthreads();
#pragma unroll
    for (int ks = 0; ks < 2; ++ks) {
      const int u = ks * 4 + (lane >> 4);
      short8 af[2], bf[4];
#pragma unroll
      for (int mi = 0; mi < 2; ++mi) {
        const int r = wr * 32 + (lane & 15) + mi * 16;
        af[mi] = *reinterpret_cast<const short8*>(
            (char*)smA + r * 128 + ((u ^ (r & 7)) * 16));
      }
#pragma unroll
      for (int ni = 0; ni < 4; ++ni) {
        const int r = wc * 64 + (lane & 15) + ni * 16;
        bf[ni] = *reinterpret_cast<const short8*>(
            (char*)smB + r * 128 + ((u ^ (r & 7)) * 16));
      }
#pragma unroll
      for (int mi = 0; mi < 2; ++mi)
#pragma unroll
        for (int ni = 0; ni < 4; ++ni)
          acc[mi][ni] = __builtin_amdgcn_mfma_f32_16x16x32_bf16(af[mi], bf[ni], acc[mi][ni], 0, 0, 0);
    }
    __syncthreads();
  }

  const int crow0 = wr * 32 + ((lane >> 4) << 2);
  const int ccol0 = wc * 64 + (lane & 15);
#pragma unroll
  for (int mi = 0; mi < 2; ++mi) {
#pragma unroll
    for (int ni = 0; ni < 4; ++ni) {
      const int col = bn + ccol0 + ni * 16;
      const float bs = (col < bsplit) ? bias[col] : bias2[col - bsplit];
#pragma unroll
      for (int r = 0; r < 4; ++r) {
        const long row = bm + crow0 + mi * 16 + r;
        float v = acc[mi][ni][r] + bs;
        if (MODE == 2) {
          ((__hip_bfloat16*)Cp)[row * N + col] = __float2bfloat16(fmaxf(v, 0.f));
        } else {
          ((__hip_bfloat16*)Cp)[row * N + col] = __float2bfloat16(v);
        }
      }
    }
  }
}

// ------------------------------------------------------------- MFMA GEMM 128x128
// Tile 128x128, BK=64, 256 thr (2x2 waves, each 64x64 = acc[4][4]).
// Same XOR-swizzle. MODE 2: bf16 + ReLU. MODE 4: bf16.
template <int MODE>
__global__ __launch_bounds__(256) void gemm128(
    const __hip_bfloat16* __restrict__ A, const __hip_bfloat16* __restrict__ Bt,
    const float* __restrict__ bias, void* __restrict__ Cp, int N, int K) {
  __shared__ short smA[128 * 64];   // 16KB
  __shared__ short smB[128 * 64];   // 16KB
  const int tid = threadIdx.x;
  const int lane = tid & 63;
  const int w = tid >> 6;
  const int wr = w >> 1, wc = w & 1;
  const long bm = (long)blockIdx.x * 128;
  const long bn = (long)blockIdx.y * 128;

  f32x4 acc[4][4];
#pragma unroll
  for (int i = 0; i < 4; ++i)
#pragma unroll
    for (int j = 0; j < 4; ++j) acc[i][j] = (f32x4)(0.f);

  const int srow = tid >> 3;                 // 0..31
  const int su = (tid & 7) ^ (srow & 7);
  const __hip_bfloat16* Ag = A + (bm + srow) * (long)K + su * 8;
  const __hip_bfloat16* Bg = Bt + (bn + srow) * (long)K + su * 8;
  char* lA = (char*)smA + tid * 16;
  char* lB = (char*)smB + tid * 16;

  for (int k0 = 0; k0 < K; k0 += 64) {
#pragma unroll
    for (int j = 0; j < 4; ++j) gload16(Ag + 32L * j * K, lA + 4096 * j);
#pragma unroll
    for (int j = 0; j < 4; ++j) gload16(Bg + 32L * j * K, lB + 4096 * j);
    Ag += 64; Bg += 64;
    __syncthreads();
#pragma unroll
    for (int ks = 0; ks < 2; ++ks) {
      const int u = ks * 4 + (lane >> 4);
      short8 af[4], bf[4];
#pragma unroll
      for (int mi = 0; mi < 4; ++mi) {
        const int r = wr * 64 + (lane & 15) + mi * 16;
        af[mi] = *reinterpret_cast<const short8*>(
            (char*)smA + r * 128 + ((u ^ (r & 7)) * 16));
      }
#pragma unroll
      for (int ni = 0; ni < 4; ++ni) {
        const int r = wc * 64 + (lane & 15) + ni * 16;
        bf[ni] = *reinterpret_cast<const short8*>(
            (char*)smB + r * 128 + ((u ^ (r & 7)) * 16));
      }
#pragma unroll
      for (int mi = 0; mi < 4; ++mi)
#pragma unroll
        for (int ni = 0; ni < 4; ++ni)
          acc[mi][ni] = __builtin_amdgcn_mfma_f32_16x16x32_bf16(af[mi], bf[ni], acc[mi][ni], 0, 0, 0);
    }
    __syncthreads();
  }

  const int crow0 = wr * 64 + ((lane >> 4) << 2);
  const int ccol0 = wc * 64 + (lane & 15);
#pragma unroll
  for (int mi = 0; mi < 4; ++mi) {
#pragma unroll
    for (int ni = 0; ni < 4; ++ni) {
      const int col = bn + ccol0 + ni * 16;
      const float bs = bias[col];
#pragma unroll
      for (int r = 0; r < 4; ++r) {
        const long row = bm + crow0 + mi * 16 + r;
        float v = acc[mi][ni][r] + bs;
        if (MODE == 2) {
          ((__hip_bfloat16*)Cp)[row * N + col] = __float2bfloat16(fmaxf(v, 0.f));
        } else {
          ((__hip_bfloat16*)Cp)[row * N + col] = __float2bfloat16(v);
        }
      }
    }
  }
}

// ------------------------------------------------------------- value GEMM
__global__ __launch_bounds__(256) void gemm_val(
    const float* __restrict__ A, const __hip_bfloat16* __restrict__ Bt,
    const float* __restrict__ bias, __hip_bfloat16* __restrict__ Cp, int Mreal) {
  __shared__ short smA[64 * 64];    // 8KB
  __shared__ short smB[256 * 64];   // 32KB
  const int tid = threadIdx.x;
  const int lane = tid & 63;
  const int w = tid >> 6;
  const long bm = (long)blockIdx.x * 64;

  f32x4 acc[4][4];
#pragma unroll
  for (int i = 0; i < 4; ++i)
#pragma unroll
    for (int j = 0; j < 4; ++j) acc[i][j] = (f32x4)(0.f);

  const int ar = tid >> 2;
  const int au = (tid & 3) * 2;
  const bool arow_ok = (bm + ar) < Mreal;
  const float* Afp = A + (bm + ar) * 256L + au * 8;
  char* wA0 = (char*)smA + ar * 128 + ((au ^ (ar & 7)) * 16);
  char* wA1 = (char*)smA + ar * 128 + (((au + 1) ^ (ar & 7)) * 16);

  const int srow = tid >> 3;
  const int su = (tid & 7) ^ (srow & 7);
  const __hip_bfloat16* Bg = Bt + (long)srow * 256 + su * 8;
  char* lB = (char*)smB + tid * 16;

  for (int k0 = 0; k0 < 256; k0 += 64) {
#pragma unroll
    for (int j = 0; j < 8; ++j) gload16(Bg + 32L * j * 256, lB + 4096 * j);
    Bg += 64;
    float4 f0 = make_float4(0.f, 0.f, 0.f, 0.f), f1 = f0, f2 = f0, f3 = f0;
    if (arow_ok) {
      f0 = *reinterpret_cast<const float4*>(Afp + k0);
      f1 = *reinterpret_cast<const float4*>(Afp + k0 + 4);
      f2 = *reinterpret_cast<const float4*>(Afp + k0 + 8);
      f3 = *reinterpret_cast<const float4*>(Afp + k0 + 12);
    }
    union { __hip_bfloat16 h[8]; uint4 u; } c0, c1;
    c0.h[0] = __float2bfloat16(f0.x); c0.h[1] = __float2bfloat16(f0.y);
    c0.h[2] = __float2bfloat16(f0.z); c0.h[3] = __float2bfloat16(f0.w);
    c0.h[4] = __float2bfloat16(f1.x); c0.h[5] = __float2bfloat16(f1.y);
    c0.h[6] = __float2bfloat16(f1.z); c0.h[7] = __float2bfloat16(f1.w);
    c1.h[0] = __float2bfloat16(f2.x); c1.h[1] = __float2bfloat16(f2.y);
    c1.h[2] = __float2bfloat16(f2.z); c1.h[3] = __float2bfloat16(f2.w);
    c1.h[4] = __float2bfloat16(f3.x); c1.h[5] = __float2bfloat16(f3.y);
    c1.h[6] = __float2bfloat16(f3.z); c1.h[7] = __float2bfloat16(f3.w);
    *reinterpret_cast<uint4*>(wA0) = c0.u;
    *reinterpret_cast<uint4*>(wA1) = c1.u;
    __syncthreads();
#pragma unroll
    for (int ks = 0; ks < 2; ++ks) {
      const int u = ks * 4 + (lane >> 4);
      short8 af[4], bf[4];
#pragma unroll
      for (int mi = 0; mi < 4; ++mi) {
        const int r = (lane & 15) + mi * 16;
        af[mi] = *reinterpret_cast<const short8*>(
            (char*)smA + r * 128 + ((u ^ (r & 7)) * 16));
      }
#pragma unroll
      for (int ni = 0; ni < 4; ++ni) {
        const int r = w * 64 + ni * 16 + (lane & 15);
        bf[ni] = *reinterpret_cast<const short8*>(
            (char*)smB + r * 128 + ((u ^ (r & 7)) * 16));
      }
#pragma unroll
      for (int mi = 0; mi < 4; ++mi)
#pragma unroll
        for (int ni = 0; ni < 4; ++ni)
          acc[mi][ni] = __builtin_amdgcn_mfma_f32_16x16x32_bf16(af[mi], bf[ni], acc[mi][ni], 0, 0, 0);
    }
    __syncthreads();
  }

  const int crow0 = (lane >> 4) << 2;
  const int cl = lane & 15;
#pragma unroll
  for (int mi = 0; mi < 4; ++mi) {
#pragma unroll
    for (int ni = 0; ni < 4; ++ni) {
      const int col = w * 64 + ni * 16 + cl;
      const float bs = bias[col];
      const int h = col >> 5, dh = col & 31;
#pragma unroll
      for (int r = 0; r < 4; ++r) {
        const long row = bm + mi * 16 + crow0 + r;
        if (row < Mreal) {
          const int b = (row >= S_) ? 1 : 0;
          const long s = row - (long)b * S_;
          Cp[(((long)(b * 8 + h)) * S_ + s) * 32 + dh] =
              __float2bfloat16(acc[mi][ni][r] + bs);
        }
      }
    }
  }
}

// ------------------------------------------------------------- ms_deform
__global__ __launch_bounds__(256) void msdeform_kernel(
    const __hip_bfloat16* __restrict__ value, const __hip_bfloat16* __restrict__ oa,
    const float* __restrict__ q_ref, const float* __restrict__ vr,
    __hip_bfloat16* __restrict__ out) {
  const int t = blockIdx.x * 256 + threadIdx.x;
  const int tid7 = t & 127;
  const int dq = tid7 & 3;
  const int l = (tid7 >> 2) & 3;
  const int h = tid7 >> 4;                                  // 0..7 (bit6 = wave)
  const int lane = threadIdx.x & 63;
  const int grp = lane & ~3;
  const int bq = __builtin_amdgcn_readfirstlane(t >> 7);
  const int b = (bq >= NQ_) ? 1 : 0;

  const int W  = (l == 0) ? 160 : (l == 1) ? 80 : (l == 2) ? 40 : 20;
  const int H  = (l == 0) ? 92  : (l == 1) ? 46 : (l == 2) ? 23 : 12;
  const int S0 = (l == 0) ? 0 : (l == 1) ? 14720 : (l == 2) ? 18400 : 19320;

  const __hip_bfloat16* oabase = oa + (long)bq * 384;
  const uint2 mu = *reinterpret_cast<const uint2*>(oabase + 256 + h * 16 + l * 4);
  const float l0 = bflo(mu.x), l1 = bfhi(mu.x), l2 = bflo(mu.y), l3 = bfhi(mu.y);
  float mx = fmaxf(fmaxf(l0, l1), fmaxf(l2, l3));
  mx = fmaxf(mx, __shfl_xor(mx, 4, 64));
  mx = fmaxf(mx, __shfl_xor(mx, 8, 64));
  const float e0 = __expf(l0 - mx), e1 = __expf(l1 - mx);
  const float e2 = __expf(l2 - mx), e3 = __expf(l3 - mx);
  float sum = e0 + e1 + e2 + e3;
  sum += __shfl_xor(sum, 4, 64);
  sum += __shfl_xor(sum, 8, 64);
  const float inv = 1.f / sum;

  const uint4 ou = *reinterpret_cast<const uint4*>(oabase + h * 32 + l * 8);

  const float rx = q_ref[(long)bq * 2 + 0];
  const float ry = q_ref[(long)bq * 2 + 1];
  const float2 vv = *reinterpret_cast<const float2*>(vr + (b * 4 + l) * 2);
  const float refxW = rx * vv.x * W - 0.5f;
  const float refyH = ry * vv.y * H - 0.5f;
  const unsigned base32 = (unsigned)(((b * 8 + h) * S_ + S0) * 32 + dq * 8);

  const float eo = (dq & 2) ? ((dq & 1) ? e3 : e2) : ((dq & 1) ? e1 : e0);
  const float aw = eo * inv;
  const unsigned ox_u = (dq & 2) ? ((dq & 1) ? ou.w : ou.z)
                                 : ((dq & 1) ? ou.y : ou.x);

  unsigned spat[4]; float wt4[4];
  {
    const float x = refxW + bflo(ox_u);
    const float y = refyH + bfhi(ox_u);
    const float x0f = floorf(x), y0f = floorf(y);
    const float lx = x - x0f, ly = y - y0f;
    const int x0 = (int)x0f, y0 = (int)y0f;
    const int x1 = x0 + 1, y1 = y0 + 1;
    const float wx0 = ((unsigned)x0 < (unsigned)W) ? (1.f - lx) : 0.f;
    const float wx1 = ((unsigned)x1 < (unsigned)W) ? lx : 0.f;
    const float wy0 = ((unsigned)y0 < (unsigned)H) ? (1.f - ly) : 0.f;
    const float wy1 = ((unsigned)y1 < (unsigned)H) ? ly : 0.f;
    const int x0c = min(max(x0, 0), W - 1);
    const int x1c = min(max(x1, 0), W - 1);
    const int y0c = min(max(y0, 0), H - 1);
    const int y1c = min(max(y1, 0), H - 1);
    spat[0] = (unsigned)(y0c * W + x0c) * 32;
    spat[1] = (unsigned)(y0c * W + x1c) * 32;
    spat[2] = (unsigned)(y1c * W + x0c) * 32;
    spat[3] = (unsigned)(y1c * W + x1c) * 32;
    wt4[0] = aw * wx0 * wy0; wt4[1] = aw * wx1 * wy0;
    wt4[2] = aw * wx0 * wy1; wt4[3] = aw * wx1 * wy1;
  }

  unsigned offs[16]; float wts[16];
#pragma unroll
  for (int s = 0; s < 4; ++s) {
    const int src = grp + s;
#pragma unroll
    for (int c = 0; c < 4; ++c) {
      offs[s * 4 + c] = base32 + (unsigned)__shfl((int)spat[c], src, 64);
      wts[s * 4 + c] = __shfl(wt4[c], src, 64);
    }
  }

  uint4 d[16];
#pragma unroll
  for (int j = 0; j < 16; ++j)
    d[j] = *reinterpret_cast<const uint4*>(value + offs[j]);
  __builtin_amdgcn_sched_barrier(0);

  f32x2 acc2[4];
#pragma unroll
  for (int i = 0; i < 4; ++i) acc2[i] = (f32x2)(0.f);
#pragma unroll
  for (int j = 0; j < 16; ++j) {
    const f32x2 ww2 = (f32x2)(wts[j]);
    f32x2 v0, v1, v2, v3;
    v0.x = bflo(d[j].x); v0.y = bfhi_raw(d[j].x);
    v1.x = bflo(d[j].y); v1.y = bfhi_raw(d[j].y);
    v2.x = bflo(d[j].z); v2.y = bfhi_raw(d[j].z);
    v3.x = bflo(d[j].w); v3.y = bfhi_raw(d[j].w);
    acc2[0] += ww2 * v0;
    acc2[1] += ww2 * v1;
    acc2[2] += ww2 * v2;
    acc2[3] += ww2 * v3;
  }

  float accf[8] = {acc2[0].x, acc2[0].y, acc2[1].x, acc2[1].y,
                   acc2[2].x, acc2[2].y, acc2[3].x, acc2[3].y};
#pragma unroll
  for (int j = 0; j < 8; ++j) accf[j] += __shfl_xor(accf[j], 4, 64);
#pragma unroll
  for (int j = 0; j < 8; ++j) accf[j] += __shfl_xor(accf[j], 8, 64);

  if (l == 0) {
    union { __hip_bfloat16 hh[8]; uint4 u; } o0;
#pragma unroll
    for (int j = 0; j < 8; ++j) o0.hh[j] = __float2bfloat16(accf[j]);
    *reinterpret_cast<uint4*>(out + (long)bq * 256 + h * 32 + dq * 8) = o0.u;
  }
}

// ------------------------------------------------------------- residual+LN
template <bool RES_F32, bool OUT_F32>
__global__ __launch_bounds__(256) void add_ln2(
    const void* __restrict__ resv, const __hip_bfloat16* __restrict__ xin,
    const float* __restrict__ gamma, const float* __restrict__ beta,
    float* __restrict__ outF, __hip_bfloat16* __restrict__ outB, int nrows) {
  int row = blockIdx.x * 4 + (threadIdx.x >> 6);
  int lane = threadIdx.x & 63;
  if (row >= nrows) return;
  float rv[4];
  if (RES_F32) {
    const float4 r4 = *reinterpret_cast<const float4*>((const float*)resv + (long)row * 256 + lane * 4);
    rv[0] = r4.x; rv[1] = r4.y; rv[2] = r4.z; rv[3] = r4.w;
  } else {
    const uint2 r2 = *reinterpret_cast<const uint2*>((const __hip_bfloat16*)resv + (long)row * 256 + lane * 4);
    rv[0] = bflo(r2.x); rv[1] = bfhi(r2.x); rv[2] = bflo(r2.y); rv[3] = bfhi(r2.y);
  }
  const uint2 x2 = *reinterpret_cast<const uint2*>(xin + (long)row * 256 + lane * 4);
  float tv[4] = {rv[0] + bflo(x2.x), rv[1] + bfhi(x2.x),
                 rv[2] + bflo(x2.y), rv[3] + bfhi(x2.y)};
  float s = tv[0] + tv[1] + tv[2] + tv[3];
#pragma unroll
  for (int o = 32; o > 0; o >>= 1) s += __shfl_xor(s, o, 64);
  float mean = s * (1.f / 256.f);
  float vs = 0.f;
#pragma unroll
  for (int j = 0; j < 4; ++j) { float dd = tv[j] - mean; vs += dd * dd; }
#pragma unroll
  for (int o = 32; o > 0; o >>= 1) vs += __shfl_xor(vs, o, 64);
  float inv = rsqrtf(vs * (1.f / 256.f) + 1e-5f);
  const float4 g = *reinterpret_cast<const float4*>(gamma + lane * 4);
  const float4 be = *reinterpret_cast<const float4*>(beta + lane * 4);
  float o4[4];
  o4[0] = (tv[0] - mean) * inv * g.x + be.x;
  o4[1] = (tv[1] - mean) * inv * g.y + be.y;
  o4[2] = (tv[2] - mean) * inv * g.z + be.z;
  o4[3] = (tv[3] - mean) * inv * g.w + be.w;
  if (OUT_F32) {
    float4 of = {o4[0], o4[1], o4[2], o4[3]};
    *reinterpret_cast<float4*>(outF + (long)row * 256 + lane * 4) = of;
  } else {
    union { __hip_bfloat16 h[4]; uint2 u; } p;
    p.h[0] = __float2bfloat16(o4[0]); p.h[1] = __float2bfloat16(o4[1]);
    p.h[2] = __float2bfloat16(o4[2]); p.h[3] = __float2bfloat16(o4[3]);
    *reinterpret_cast<uint2*>(outB + (long)row * 256 + lane * 4) = p.u;
  }
}

// ------------------------------------------------------------- launch
extern "C" void kernel_launch(void* const* d_in, const int* in_sizes, int n_in,
                              void* d_out, int out_size, void* d_ws, size_t ws_size,
                              hipStream_t stream) {
  const float* src    = (const float*)d_in[0];
  const float* q_feat = (const float*)d_in[1];
  const float* q_pos  = (const float*)d_in[2];
  const float* q_ref  = (const float*)d_in[3];
  const float* vr     = (const float*)d_in[4];
  const float* Wv     = (const float*)d_in[5];
  const float* bv     = (const float*)d_in[6];
  const float* Woff   = (const float*)d_in[7];
  const float* boff   = (const float*)d_in[8];
  const float* Wa     = (const float*)d_in[9];
  const float* ba     = (const float*)d_in[10];
  const float* Wo     = (const float*)d_in[11];
  const float* bo     = (const float*)d_in[12];
  const float* g1     = (const float*)d_in[13];
  const float* be1    = (const float*)d_in[14];
  const float* W1     = (const float*)d_in[15];
  const float* bf1    = (const float*)d_in[16];
  const float* W2     = (const float*)d_in[17];
  const float* bf2    = (const float*)d_in[18];
  const float* g2     = (const float*)d_in[19];
  const float* be2    = (const float*)d_in[20];

  char* ws = (char*)d_ws;
  __hip_bfloat16* val_bf = (__hip_bfloat16*)(ws + 0);          // [..msdeform]
  __hip_bfloat16* q_bf   = (__hip_bfloat16*)(ws + 20029440);   // [..oa gemm]
  __hip_bfloat16* a_bf   = (__hip_bfloat16*)(ws + 0);          // [proj..ln1]
  __hip_bfloat16* h1_bf  = (__hip_bfloat16*)(ws + 0);          // [ffn1..ffn2]
  __hip_bfloat16* oa_bf  = (__hip_bfloat16*)(ws + 41943040);   // [..msdeform]
  __hip_bfloat16* f2_bf  = (__hip_bfloat16*)(ws + 41943040);   // [ffn2..ln2]
  __hip_bfloat16* ms_bf  = (__hip_bfloat16*)(ws + 57671680);   // [..proj]
  __hip_bfloat16* x_bf   = (__hip_bfloat16*)(ws + 68157440);   // [ln1..ln2]
  __hip_bfloat16* wts    = (__hip_bfloat16*)(ws + 78643200);
  float* outp = (float*)d_out;

  const int Mq = B_ * NQ_;   // 20000
  const int Mv = B_ * S_;    // 39120
  const int BIG = 1 << 30;

  prep_all<<<184 + MQ_P * 32 / 256, 256, 0, stream>>>(Wv, Woff, Wa, Wo, W1, W2, wts,
                                                      q_feat, q_pos, q_bf);
  gemm_val<<<MV_P / 64, 256, 0, stream>>>(src, wts + 0, bv, val_bf, Mv);
  gemm_bf16<4><<<dim3(MQ_P / 64, 3), 256, 0, stream>>>(q_bf, wts + 65536, boff, ba, 256, oa_bf, MQ_P, 384, 256);
  msdeform_kernel<<<(Mq * 128) / 256, 256, 0, stream>>>(val_bf, oa_bf, q_ref, vr, ms_bf);
  gemm_bf16<4><<<dim3(MQ_P / 64, 2), 256, 0, stream>>>(ms_bf, wts + 163840, bo, bo, BIG, a_bf, MQ_P, 256, 256);
  add_ln2<true, false><<<(Mq + 3) / 4, 256, 0, stream>>>(q_feat, a_bf, g1, be1, nullptr, x_bf, Mq);
  // h1 = relu(x @ W1 + bf1)  (128x128 tile)
  gemm128<2><<<dim3(MQ_P / 128, 8), 256, 0, stream>>>(x_bf, wts + 229376, bf1, h1_bf, 1024, 256);
  // f2 = h1 @ W2 + bf2  (128x128 tile)
  gemm128<4><<<dim3(MQ_P / 128, 2), 256, 0, stream>>>(h1_bf, wts + 491520, bf2, f2_bf, 256, 1024);
  add_ln2<false, true><<<(Mq + 3) / 4, 256, 0, stream>>>(x_bf, f2_bf, g2, be2, outp, nullptr, Mq);
}

// Round 14
// 149.160 us; speedup vs baseline: 1.0358x; 1.0358x over previous
//
#include <hip/hip_runtime.h>
#include <hip/hip_bf16.h>
#include <cstdint>

#define B_   2
#define NQ_  10000
#define C_   256
#define NH_  8
#define DH_  32
#define DFF_ 1024
#define S_   19560
#define MQ_P 20480   // 160*128 / 320*64 tiles; %8==0 -> stable row->XCD map
#define MV_P 39168   // 306*128

typedef __attribute__((ext_vector_type(8))) short short8;
typedef __attribute__((ext_vector_type(4))) float f32x4;
typedef __attribute__((ext_vector_type(2))) float f32x2;

__device__ __forceinline__ void gload16(const void* g, void* l) {
  __builtin_amdgcn_global_load_lds(
      (const __attribute__((address_space(1))) unsigned int*)g,
      (__attribute__((address_space(3))) unsigned int*)l, 16, 0, 0);
}

__device__ __forceinline__ float bflo(unsigned u) {
  union { unsigned u; float f; } c; c.u = u << 16; return c.f;
}
__device__ __forceinline__ float bfhi(unsigned u) {
  union { unsigned u; float f; } c; c.u = u & 0xffff0000u; return c.f;
}
__device__ __forceinline__ float bfhi_raw(unsigned u) {
  union { unsigned u; float f; } c; c.u = u; return c.f;
}

// ------------------------------------------------------------- prep (fused)
__global__ __launch_bounds__(256) void prep_all(
    const float* __restrict__ Wv, const float* __restrict__ Woff,
    const float* __restrict__ Wa, const float* __restrict__ Wo,
    const float* __restrict__ W1, const float* __restrict__ W2,
    __hip_bfloat16* __restrict__ wbase,
    const float* __restrict__ qf, const float* __restrict__ qp,
    __hip_bfloat16* __restrict__ q_bf) {
  __shared__ float tile[64][65];
  if (blockIdx.x < 184) {
    int blk = blockIdx.x;
    const float* W; __hip_bfloat16* Wt; int K, N;
    if (blk < 16)       { W = Wv;   Wt = wbase + 0;      K = 256;  N = 256; }
    else if (blk < 32)  { W = Woff; Wt = wbase + 65536;  K = 256;  N = 256;  blk -= 16; }
    else if (blk < 40)  { W = Wa;   Wt = wbase + 131072; K = 256;  N = 128;  blk -= 32; }
    else if (blk < 56)  { W = Wo;   Wt = wbase + 163840; K = 256;  N = 256;  blk -= 40; }
    else if (blk < 120) { W = W1;   Wt = wbase + 229376; K = 256;  N = 1024; blk -= 56; }
    else                { W = W2;   Wt = wbase + 491520; K = 1024; N = 256;  blk -= 120; }
    const int ntiles = N >> 6;
    const int kt = blk / ntiles, nt = blk % ntiles;
    const int c = threadIdx.x & 63, r0 = threadIdx.x >> 6;
#pragma unroll
    for (int i = 0; i < 16; ++i) {
      const int r = r0 + i * 4;
      tile[r][c] = W[(long)(kt * 64 + r) * N + nt * 64 + c];
    }
    __syncthreads();
#pragma unroll
    for (int i = 0; i < 16; ++i) {
      const int n = r0 + i * 4;
      Wt[(long)(nt * 64 + n) * K + kt * 64 + c] = __float2bfloat16(tile[c][n]);
    }
  } else {
    long idx = (long)(blockIdx.x - 184) * 256 + threadIdx.x;
    int row = idx >> 5, c8 = (idx & 31) * 8;
    union { __hip_bfloat16 h[8]; uint4 u; } o;
    if (row < B_ * NQ_) {
      const float4 a0 = *reinterpret_cast<const float4*>(qf + (long)row * 256 + c8);
      const float4 a1 = *reinterpret_cast<const float4*>(qf + (long)row * 256 + c8 + 4);
      const float4 b0 = *reinterpret_cast<const float4*>(qp + (long)row * 256 + c8);
      const float4 b1 = *reinterpret_cast<const float4*>(qp + (long)row * 256 + c8 + 4);
      o.h[0] = __float2bfloat16(a0.x + b0.x); o.h[1] = __float2bfloat16(a0.y + b0.y);
      o.h[2] = __float2bfloat16(a0.z + b0.z); o.h[3] = __float2bfloat16(a0.w + b0.w);
      o.h[4] = __float2bfloat16(a1.x + b1.x); o.h[5] = __float2bfloat16(a1.y + b1.y);
      o.h[6] = __float2bfloat16(a1.z + b1.z); o.h[7] = __float2bfloat16(a1.w + b1.w);
    } else o.u = make_uint4(0, 0, 0, 0);
    if (row < MQ_P) *reinterpret_cast<uint4*>(q_bf + (long)row * 256 + c8) = o.u;
  }
}

// ------------------------------------------------------------- MFMA GEMM 64x128
// Tile 64x128, BK=64, 256 thr (2x2 waves), XOR-swizzled LDS.
// MODE 2: bf16 out + ReLU. MODE 4: bf16 out.
template <int MODE>
__global__ __launch_bounds__(256) void gemm_bf16(
    const __hip_bfloat16* __restrict__ A, const __hip_bfloat16* __restrict__ Bt,
    const float* __restrict__ bias, const float* __restrict__ bias2, int bsplit,
    void* __restrict__ Cp, int M, int N, int K) {
  __shared__ short smA[64 * 64];    // 8KB
  __shared__ short smB[128 * 64];   // 16KB
  const int tid = threadIdx.x;
  const int lane = tid & 63;
  const int w = tid >> 6;
  const int wr = w >> 1, wc = w & 1;
  const long bm = (long)blockIdx.x * 64;
  const long bn = (long)blockIdx.y * 128;

  f32x4 acc[2][4];
#pragma unroll
  for (int i = 0; i < 2; ++i)
#pragma unroll
    for (int j = 0; j < 4; ++j) acc[i][j] = (f32x4)(0.f);

  const int srow = tid >> 3;
  const int su = (tid & 7) ^ (srow & 7);
  const __hip_bfloat16* Ag = A + (bm + srow) * (long)K + su * 8;
  const __hip_bfloat16* Bg = Bt + (bn + srow) * (long)K + su * 8;
  char* lA = (char*)smA + tid * 16;
  char* lB = (char*)smB + tid * 16;

  for (int k0 = 0; k0 < K; k0 += 64) {
    gload16(Ag,           lA);
    gload16(Ag + 32L * K, lA + 4096);
    gload16(Bg,           lB);
    gload16(Bg + 32L * K, lB + 4096);
    gload16(Bg + 64L * K, lB + 8192);
    gload16(Bg + 96L * K, lB + 12288);
    Ag += 64; Bg += 64;
    __syncthreads();
#pragma unroll
    for (int ks = 0; ks < 2; ++ks) {
      const int u = ks * 4 + (lane >> 4);
      short8 af[2], bf[4];
#pragma unroll
      for (int mi = 0; mi < 2; ++mi) {
        const int r = wr * 32 + (lane & 15) + mi * 16;
        af[mi] = *reinterpret_cast<const short8*>(
            (char*)smA + r * 128 + ((u ^ (r & 7)) * 16));
      }
#pragma unroll
      for (int ni = 0; ni < 4; ++ni) {
        const int r = wc * 64 + (lane & 15) + ni * 16;
        bf[ni] = *reinterpret_cast<const short8*>(
            (char*)smB + r * 128 + ((u ^ (r & 7)) * 16));
      }
#pragma unroll
      for (int mi = 0; mi < 2; ++mi)
#pragma unroll
        for (int ni = 0; ni < 4; ++ni)
          acc[mi][ni] = __builtin_amdgcn_mfma_f32_16x16x32_bf16(af[mi], bf[ni], acc[mi][ni], 0, 0, 0);
    }
    __syncthreads();
  }

  const int crow0 = wr * 32 + ((lane >> 4) << 2);
  const int ccol0 = wc * 64 + (lane & 15);
#pragma unroll
  for (int mi = 0; mi < 2; ++mi) {
#pragma unroll
    for (int ni = 0; ni < 4; ++ni) {
      const int col = bn + ccol0 + ni * 16;
      const float bs = (col < bsplit) ? bias[col] : bias2[col - bsplit];
#pragma unroll
      for (int r = 0; r < 4; ++r) {
        const long row = bm + crow0 + mi * 16 + r;
        float v = acc[mi][ni][r] + bs;
        if (MODE == 2) {
          ((__hip_bfloat16*)Cp)[row * N + col] = __float2bfloat16(fmaxf(v, 0.f));
        } else {
          ((__hip_bfloat16*)Cp)[row * N + col] = __float2bfloat16(v);
        }
      }
    }
  }
}

// ------------------------------------------------------------- MFMA GEMM 128x128
// Tile 128x128, BK=64, 256 thr (2x2 waves, each 64x64 = acc[4][4]).
template <int MODE>
__global__ __launch_bounds__(256) void gemm128(
    const __hip_bfloat16* __restrict__ A, const __hip_bfloat16* __restrict__ Bt,
    const float* __restrict__ bias, void* __restrict__ Cp, int N, int K) {
  __shared__ short smA[128 * 64];   // 16KB
  __shared__ short smB[128 * 64];   // 16KB
  const int tid = threadIdx.x;
  const int lane = tid & 63;
  const int w = tid >> 6;
  const int wr = w >> 1, wc = w & 1;
  const long bm = (long)blockIdx.x * 128;
  const long bn = (long)blockIdx.y * 128;

  f32x4 acc[4][4];
#pragma unroll
  for (int i = 0; i < 4; ++i)
#pragma unroll
    for (int j = 0; j < 4; ++j) acc[i][j] = (f32x4)(0.f);

  const int srow = tid >> 3;                 // 0..31
  const int su = (tid & 7) ^ (srow & 7);
  const __hip_bfloat16* Ag = A + (bm + srow) * (long)K + su * 8;
  const __hip_bfloat16* Bg = Bt + (bn + srow) * (long)K + su * 8;
  char* lA = (char*)smA + tid * 16;
  char* lB = (char*)smB + tid * 16;

  for (int k0 = 0; k0 < K; k0 += 64) {
#pragma unroll
    for (int j = 0; j < 4; ++j) gload16(Ag + 32L * j * K, lA + 4096 * j);
#pragma unroll
    for (int j = 0; j < 4; ++j) gload16(Bg + 32L * j * K, lB + 4096 * j);
    Ag += 64; Bg += 64;
    __syncthreads();
#pragma unroll
    for (int ks = 0; ks < 2; ++ks) {
      const int u = ks * 4 + (lane >> 4);
      short8 af[4], bf[4];
#pragma unroll
      for (int mi = 0; mi < 4; ++mi) {
        const int r = wr * 64 + (lane & 15) + mi * 16;
        af[mi] = *reinterpret_cast<const short8*>(
            (char*)smA + r * 128 + ((u ^ (r & 7)) * 16));
      }
#pragma unroll
      for (int ni = 0; ni < 4; ++ni) {
        const int r = wc * 64 + (lane & 15) + ni * 16;
        bf[ni] = *reinterpret_cast<const short8*>(
            (char*)smB + r * 128 + ((u ^ (r & 7)) * 16));
      }
#pragma unroll
      for (int mi = 0; mi < 4; ++mi)
#pragma unroll
        for (int ni = 0; ni < 4; ++ni)
          acc[mi][ni] = __builtin_amdgcn_mfma_f32_16x16x32_bf16(af[mi], bf[ni], acc[mi][ni], 0, 0, 0);
    }
    __syncthreads();
  }

  const int crow0 = wr * 64 + ((lane >> 4) << 2);
  const int ccol0 = wc * 64 + (lane & 15);
#pragma unroll
  for (int mi = 0; mi < 4; ++mi) {
#pragma unroll
    for (int ni = 0; ni < 4; ++ni) {
      const int col = bn + ccol0 + ni * 16;
      const float bs = bias[col];
#pragma unroll
      for (int r = 0; r < 4; ++r) {
        const long row = bm + crow0 + mi * 16 + r;
        float v = acc[mi][ni][r] + bs;
        if (MODE == 2) {
          ((__hip_bfloat16*)Cp)[row * N + col] = __float2bfloat16(fmaxf(v, 0.f));
        } else {
          ((__hip_bfloat16*)Cp)[row * N + col] = __float2bfloat16(v);
        }
      }
    }
  }
}

// ------------------------------------------------------------- value GEMM
__global__ __launch_bounds__(256) void gemm_val(
    const float* __restrict__ A, const __hip_bfloat16* __restrict__ Bt,
    const float* __restrict__ bias, __hip_bfloat16* __restrict__ Cp, int Mreal) {
  __shared__ short smA[64 * 64];    // 8KB
  __shared__ short smB[256 * 64];   // 32KB
  const int tid = threadIdx.x;
  const int lane = tid & 63;
  const int w = tid >> 6;
  const long bm = (long)blockIdx.x * 64;

  f32x4 acc[4][4];
#pragma unroll
  for (int i = 0; i < 4; ++i)
#pragma unroll
    for (int j = 0; j < 4; ++j) acc[i][j] = (f32x4)(0.f);

  const int ar = tid >> 2;
  const int au = (tid & 3) * 2;
  const bool arow_ok = (bm + ar) < Mreal;
  const float* Afp = A + (bm + ar) * 256L + au * 8;
  char* wA0 = (char*)smA + ar * 128 + ((au ^ (ar & 7)) * 16);
  char* wA1 = (char*)smA + ar * 128 + (((au + 1) ^ (ar & 7)) * 16);

  const int srow = tid >> 3;
  const int su = (tid & 7) ^ (srow & 7);
  const __hip_bfloat16* Bg = Bt + (long)srow * 256 + su * 8;
  char* lB = (char*)smB + tid * 16;

  for (int k0 = 0; k0 < 256; k0 += 64) {
#pragma unroll
    for (int j = 0; j < 8; ++j) gload16(Bg + 32L * j * 256, lB + 4096 * j);
    Bg += 64;
    float4 f0 = make_float4(0.f, 0.f, 0.f, 0.f), f1 = f0, f2 = f0, f3 = f0;
    if (arow_ok) {
      f0 = *reinterpret_cast<const float4*>(Afp + k0);
      f1 = *reinterpret_cast<const float4*>(Afp + k0 + 4);
      f2 = *reinterpret_cast<const float4*>(Afp + k0 + 8);
      f3 = *reinterpret_cast<const float4*>(Afp + k0 + 12);
    }
    union { __hip_bfloat16 h[8]; uint4 u; } c0, c1;
    c0.h[0] = __float2bfloat16(f0.x); c0.h[1] = __float2bfloat16(f0.y);
    c0.h[2] = __float2bfloat16(f0.z); c0.h[3] = __float2bfloat16(f0.w);
    c0.h[4] = __float2bfloat16(f1.x); c0.h[5] = __float2bfloat16(f1.y);
    c0.h[6] = __float2bfloat16(f1.z); c0.h[7] = __float2bfloat16(f1.w);
    c1.h[0] = __float2bfloat16(f2.x); c1.h[1] = __float2bfloat16(f2.y);
    c1.h[2] = __float2bfloat16(f2.z); c1.h[3] = __float2bfloat16(f2.w);
    c1.h[4] = __float2bfloat16(f3.x); c1.h[5] = __float2bfloat16(f3.y);
    c1.h[6] = __float2bfloat16(f3.z); c1.h[7] = __float2bfloat16(f3.w);
    *reinterpret_cast<uint4*>(wA0) = c0.u;
    *reinterpret_cast<uint4*>(wA1) = c1.u;
    __syncthreads();
#pragma unroll
    for (int ks = 0; ks < 2; ++ks) {
      const int u = ks * 4 + (lane >> 4);
      short8 af[4], bf[4];
#pragma unroll
      for (int mi = 0; mi < 4; ++mi) {
        const int r = (lane & 15) + mi * 16;
        af[mi] = *reinterpret_cast<const short8*>(
            (char*)smA + r * 128 + ((u ^ (r & 7)) * 16));
      }
#pragma unroll
      for (int ni = 0; ni < 4; ++ni) {
        const int r = w * 64 + ni * 16 + (lane & 15);
        bf[ni] = *reinterpret_cast<const short8*>(
            (char*)smB + r * 128 + ((u ^ (r & 7)) * 16));
      }
#pragma unroll
      for (int mi = 0; mi < 4; ++mi)
#pragma unroll
        for (int ni = 0; ni < 4; ++ni)
          acc[mi][ni] = __builtin_amdgcn_mfma_f32_16x16x32_bf16(af[mi], bf[ni], acc[mi][ni], 0, 0, 0);
    }
    __syncthreads();
  }

  const int crow0 = (lane >> 4) << 2;
  const int cl = lane & 15;
#pragma unroll
  for (int mi = 0; mi < 4; ++mi) {
#pragma unroll
    for (int ni = 0; ni < 4; ++ni) {
      const int col = w * 64 + ni * 16 + cl;
      const float bs = bias[col];
      const int h = col >> 5, dh = col & 31;
#pragma unroll
      for (int r = 0; r < 4; ++r) {
        const long row = bm + mi * 16 + crow0 + r;
        if (row < Mreal) {
          const int b = (row >= S_) ? 1 : 0;
          const long s = row - (long)b * S_;
          Cp[(((long)(b * 8 + h)) * S_ + s) * 32 + dh] =
              __float2bfloat16(acc[mi][ni][r] + bs);
        }
      }
    }
  }
}

// ------------------------------------------------------------- ms_deform
__global__ __launch_bounds__(256) void msdeform_kernel(
    const __hip_bfloat16* __restrict__ value, const __hip_bfloat16* __restrict__ oa,
    const float* __restrict__ q_ref, const float* __restrict__ vr,
    __hip_bfloat16* __restrict__ out) {
  const int t = blockIdx.x * 256 + threadIdx.x;
  const int tid7 = t & 127;
  const int dq = tid7 & 3;
  const int l = (tid7 >> 2) & 3;
  const int h = tid7 >> 4;
  const int lane = threadIdx.x & 63;
  const int grp = lane & ~3;
  const int bq = __builtin_amdgcn_readfirstlane(t >> 7);
  const int b = (bq >= NQ_) ? 1 : 0;

  const int W  = (l == 0) ? 160 : (l == 1) ? 80 : (l == 2) ? 40 : 20;
  const int H  = (l == 0) ? 92  : (l == 1) ? 46 : (l == 2) ? 23 : 12;
  const int S0 = (l == 0) ? 0 : (l == 1) ? 14720 : (l == 2) ? 18400 : 19320;

  const __hip_bfloat16* oabase = oa + (long)bq * 384;
  const uint2 mu = *reinterpret_cast<const uint2*>(oabase + 256 + h * 16 + l * 4);
  const float l0 = bflo(mu.x), l1 = bfhi(mu.x), l2 = bflo(mu.y), l3 = bfhi(mu.y);
  float mx = fmaxf(fmaxf(l0, l1), fmaxf(l2, l3));
  mx = fmaxf(mx, __shfl_xor(mx, 4, 64));
  mx = fmaxf(mx, __shfl_xor(mx, 8, 64));
  const float e0 = __expf(l0 - mx), e1 = __expf(l1 - mx);
  const float e2 = __expf(l2 - mx), e3 = __expf(l3 - mx);
  float sum = e0 + e1 + e2 + e3;
  sum += __shfl_xor(sum, 4, 64);
  sum += __shfl_xor(sum, 8, 64);
  const float inv = 1.f / sum;

  const uint4 ou = *reinterpret_cast<const uint4*>(oabase + h * 32 + l * 8);

  const float rx = q_ref[(long)bq * 2 + 0];
  const float ry = q_ref[(long)bq * 2 + 1];
  const float2 vv = *reinterpret_cast<const float2*>(vr + (b * 4 + l) * 2);
  const float refxW = rx * vv.x * W - 0.5f;
  const float refyH = ry * vv.y * H - 0.5f;
  const unsigned base32 = (unsigned)(((b * 8 + h) * S_ + S0) * 32 + dq * 8);

  const float eo = (dq & 2) ? ((dq & 1) ? e3 : e2) : ((dq & 1) ? e1 : e0);
  const float aw = eo * inv;
  const unsigned ox_u = (dq & 2) ? ((dq & 1) ? ou.w : ou.z)
                                 : ((dq & 1) ? ou.y : ou.x);

  unsigned spat[4]; float wt4[4];
  {
    const float x = refxW + bflo(ox_u);
    const float y = refyH + bfhi(ox_u);
    const float x0f = floorf(x), y0f = floorf(y);
    const float lx = x - x0f, ly = y - y0f;
    const int x0 = (int)x0f, y0 = (int)y0f;
    const int x1 = x0 + 1, y1 = y0 + 1;
    const float wx0 = ((unsigned)x0 < (unsigned)W) ? (1.f - lx) : 0.f;
    const float wx1 = ((unsigned)x1 < (unsigned)W) ? lx : 0.f;
    const float wy0 = ((unsigned)y0 < (unsigned)H) ? (1.f - ly) : 0.f;
    const float wy1 = ((unsigned)y1 < (unsigned)H) ? ly : 0.f;
    const int x0c = min(max(x0, 0), W - 1);
    const int x1c = min(max(x1, 0), W - 1);
    const int y0c = min(max(y0, 0), H - 1);
    const int y1c = min(max(y1, 0), H - 1);
    spat[0] = (unsigned)(y0c * W + x0c) * 32;
    spat[1] = (unsigned)(y0c * W + x1c) * 32;
    spat[2] = (unsigned)(y1c * W + x0c) * 32;
    spat[3] = (unsigned)(y1c * W + x1c) * 32;
    wt4[0] = aw * wx0 * wy0; wt4[1] = aw * wx1 * wy0;
    wt4[2] = aw * wx0 * wy1; wt4[3] = aw * wx1 * wy1;
  }

  unsigned offs[16]; float wts[16];
#pragma unroll
  for (int s = 0; s < 4; ++s) {
    const int src = grp + s;
#pragma unroll
    for (int c = 0; c < 4; ++c) {
      offs[s * 4 + c] = base32 + (unsigned)__shfl((int)spat[c], src, 64);
      wts[s * 4 + c] = __shfl(wt4[c], src, 64);
    }
  }

  uint4 d[16];
#pragma unroll
  for (int j = 0; j < 16; ++j)
    d[j] = *reinterpret_cast<const uint4*>(value + offs[j]);
  __builtin_amdgcn_sched_barrier(0);

  f32x2 acc2[4];
#pragma unroll
  for (int i = 0; i < 4; ++i) acc2[i] = (f32x2)(0.f);
#pragma unroll
  for (int j = 0; j < 16; ++j) {
    const f32x2 ww2 = (f32x2)(wts[j]);
    f32x2 v0, v1, v2, v3;
    v0.x = bflo(d[j].x); v0.y = bfhi_raw(d[j].x);
    v1.x = bflo(d[j].y); v1.y = bfhi_raw(d[j].y);
    v2.x = bflo(d[j].z); v2.y = bfhi_raw(d[j].z);
    v3.x = bflo(d[j].w); v3.y = bfhi_raw(d[j].w);
    acc2[0] += ww2 * v0;
    acc2[1] += ww2 * v1;
    acc2[2] += ww2 * v2;
    acc2[3] += ww2 * v3;
  }

  float accf[8] = {acc2[0].x, acc2[0].y, acc2[1].x, acc2[1].y,
                   acc2[2].x, acc2[2].y, acc2[3].x, acc2[3].y};
#pragma unroll
  for (int j = 0; j < 8; ++j) accf[j] += __shfl_xor(accf[j], 4, 64);
#pragma unroll
  for (int j = 0; j < 8; ++j) accf[j] += __shfl_xor(accf[j], 8, 64);

  if (l == 0) {
    union { __hip_bfloat16 hh[8]; uint4 u; } o0;
#pragma unroll
    for (int j = 0; j < 8; ++j) o0.hh[j] = __float2bfloat16(accf[j]);
    *reinterpret_cast<uint4*>(out + (long)bq * 256 + h * 32 + dq * 8) = o0.u;
  }
}

// ------------------------------------------------------------- residual+LN
template <bool RES_F32, bool OUT_F32>
__global__ __launch_bounds__(256) void add_ln2(
    const void* __restrict__ resv, const __hip_bfloat16* __restrict__ xin,
    const float* __restrict__ gamma, const float* __restrict__ beta,
    float* __restrict__ outF, __hip_bfloat16* __restrict__ outB, int nrows) {
  int row = blockIdx.x * 4 + (threadIdx.x >> 6);
  int lane = threadIdx.x & 63;
  if (row >= nrows) return;
  float rv[4];
  if (RES_F32) {
    const float4 r4 = *reinterpret_cast<const float4*>((const float*)resv + (long)row * 256 + lane * 4);
    rv[0] = r4.x; rv[1] = r4.y; rv[2] = r4.z; rv[3] = r4.w;
  } else {
    const uint2 r2 = *reinterpret_cast<const uint2*>((const __hip_bfloat16*)resv + (long)row * 256 + lane * 4);
    rv[0] = bflo(r2.x); rv[1] = bfhi(r2.x); rv[2] = bflo(r2.y); rv[3] = bfhi(r2.y);
  }
  const uint2 x2 = *reinterpret_cast<const uint2*>(xin + (long)row * 256 + lane * 4);
  float tv[4] = {rv[0] + bflo(x2.x), rv[1] + bfhi(x2.x),
                 rv[2] + bflo(x2.y), rv[3] + bfhi(x2.y)};
  float s = tv[0] + tv[1] + tv[2] + tv[3];
#pragma unroll
  for (int o = 32; o > 0; o >>= 1) s += __shfl_xor(s, o, 64);
  float mean = s * (1.f / 256.f);
  float vs = 0.f;
#pragma unroll
  for (int j = 0; j < 4; ++j) { float dd = tv[j] - mean; vs += dd * dd; }
#pragma unroll
  for (int o = 32; o > 0; o >>= 1) vs += __shfl_xor(vs, o, 64);
  float inv = rsqrtf(vs * (1.f / 256.f) + 1e-5f);
  const float4 g = *reinterpret_cast<const float4*>(gamma + lane * 4);
  const float4 be = *reinterpret_cast<const float4*>(beta + lane * 4);
  float o4[4];
  o4[0] = (tv[0] - mean) * inv * g.x + be.x;
  o4[1] = (tv[1] - mean) * inv * g.y + be.y;
  o4[2] = (tv[2] - mean) * inv * g.z + be.z;
  o4[3] = (tv[3] - mean) * inv * g.w + be.w;
  if (OUT_F32) {
    float4 of = {o4[0], o4[1], o4[2], o4[3]};
    *reinterpret_cast<float4*>(outF + (long)row * 256 + lane * 4) = of;
  } else {
    union { __hip_bfloat16 h[4]; uint2 u; } p;
    p.h[0] = __float2bfloat16(o4[0]); p.h[1] = __float2bfloat16(o4[1]);
    p.h[2] = __float2bfloat16(o4[2]); p.h[3] = __float2bfloat16(o4[3]);
    *reinterpret_cast<uint2*>(outB + (long)row * 256 + lane * 4) = p.u;
  }
}

// ------------------------------------------------------------- launch
extern "C" void kernel_launch(void* const* d_in, const int* in_sizes, int n_in,
                              void* d_out, int out_size, void* d_ws, size_t ws_size,
                              hipStream_t stream) {
  const float* src    = (const float*)d_in[0];
  const float* q_feat = (const float*)d_in[1];
  const float* q_pos  = (const float*)d_in[2];
  const float* q_ref  = (const float*)d_in[3];
  const float* vr     = (const float*)d_in[4];
  const float* Wv     = (const float*)d_in[5];
  const float* bv     = (const float*)d_in[6];
  const float* Woff   = (const float*)d_in[7];
  const float* boff   = (const float*)d_in[8];
  const float* Wa     = (const float*)d_in[9];
  const float* ba     = (const float*)d_in[10];
  const float* Wo     = (const float*)d_in[11];
  const float* bo     = (const float*)d_in[12];
  const float* g1     = (const float*)d_in[13];
  const float* be1    = (const float*)d_in[14];
  const float* W1     = (const float*)d_in[15];
  const float* bf1    = (const float*)d_in[16];
  const float* W2     = (const float*)d_in[17];
  const float* bf2    = (const float*)d_in[18];
  const float* g2     = (const float*)d_in[19];
  const float* be2    = (const float*)d_in[20];

  char* ws = (char*)d_ws;
  __hip_bfloat16* val_bf = (__hip_bfloat16*)(ws + 0);          // [..msdeform]
  __hip_bfloat16* q_bf   = (__hip_bfloat16*)(ws + 20029440);   // [..oa gemm]
  __hip_bfloat16* a_bf   = (__hip_bfloat16*)(ws + 0);          // [proj..ln1]
  __hip_bfloat16* h1_bf  = (__hip_bfloat16*)(ws + 0);          // [ffn1..ffn2]
  __hip_bfloat16* oa_bf  = (__hip_bfloat16*)(ws + 41943040);   // [..msdeform]
  __hip_bfloat16* f2_bf  = (__hip_bfloat16*)(ws + 41943040);   // [ffn2..ln2]
  __hip_bfloat16* ms_bf  = (__hip_bfloat16*)(ws + 57671680);   // [..proj]
  __hip_bfloat16* x_bf   = (__hip_bfloat16*)(ws + 68157440);   // [ln1..ln2]
  __hip_bfloat16* wts    = (__hip_bfloat16*)(ws + 78643200);
  float* outp = (float*)d_out;

  const int Mq = B_ * NQ_;   // 20000
  const int Mv = B_ * S_;    // 39120
  const int BIG = 1 << 30;

  prep_all<<<184 + MQ_P * 32 / 256, 256, 0, stream>>>(Wv, Woff, Wa, Wo, W1, W2, wts,
                                                      q_feat, q_pos, q_bf);
  gemm_val<<<MV_P / 64, 256, 0, stream>>>(src, wts + 0, bv, val_bf, Mv);
  gemm_bf16<4><<<dim3(MQ_P / 64, 3), 256, 0, stream>>>(q_bf, wts + 65536, boff, ba, 256, oa_bf, MQ_P, 384, 256);
  msdeform_kernel<<<(Mq * 128) / 256, 256, 0, stream>>>(val_bf, oa_bf, q_ref, vr, ms_bf);
  gemm_bf16<4><<<dim3(MQ_P / 64, 2), 256, 0, stream>>>(ms_bf, wts + 163840, bo, bo, BIG, a_bf, MQ_P, 256, 256);
  add_ln2<true, false><<<(Mq + 3) / 4, 256, 0, stream>>>(q_feat, a_bf, g1, be1, nullptr, x_bf, Mq);
  // h1 = relu(x @ W1 + bf1)  (128x128 tile: 1280 blocks, 5/CU)
  gemm128<2><<<dim3(MQ_P / 128, 8), 256, 0, stream>>>(x_bf, wts + 229376, bf1, h1_bf, 1024, 256);
  // f2 = h1 @ W2 + bf2  (64x128 tile: 640 blocks, 2.5/CU)
  gemm_bf16<4><<<dim3(MQ_P / 64, 2), 256, 0, stream>>>(h1_bf, wts + 491520, bf2, bf2, BIG, f2_bf, MQ_P, 256, 1024);
  add_ln2<false, true><<<(Mq + 3) / 4, 256, 0, stream>>>(x_bf, f2_bf, g2, be2, outp, nullptr, Mq);
}

// Round 15
// 146.798 us; speedup vs baseline: 1.0525x; 1.0161x over previous
//
#include <hip/hip_runtime.h>
#include <hip/hip_bf16.h>
#include <cstdint>

#define B_   2
#define NQ_  10000
#define C_   256
#define NH_  8
#define DH_  32
#define DFF_ 1024
#define S_   19560
#define MQ_P 20480   // 320*64 tiles; %8==0 -> stable row->XCD map
#define MV_P 39168   // 612*64

typedef __attribute__((ext_vector_type(8))) short short8;
typedef __attribute__((ext_vector_type(4))) float f32x4;
typedef __attribute__((ext_vector_type(2))) float f32x2;

__device__ __forceinline__ void gload16(const void* g, void* l) {
  __builtin_amdgcn_global_load_lds(
      (const __attribute__((address_space(1))) unsigned int*)g,
      (__attribute__((address_space(3))) unsigned int*)l, 16, 0, 0);
}

__device__ __forceinline__ float bflo(unsigned u) {
  union { unsigned u; float f; } c; c.u = u << 16; return c.f;
}
__device__ __forceinline__ float bfhi(unsigned u) {
  union { unsigned u; float f; } c; c.u = u & 0xffff0000u; return c.f;
}
__device__ __forceinline__ float bfhi_raw(unsigned u) {
  union { unsigned u; float f; } c; c.u = u; return c.f;
}

// ------------------------------------------------------------- weight transpose
__global__ __launch_bounds__(256) void prep_w(
    const float* __restrict__ Wv, const float* __restrict__ Woff,
    const float* __restrict__ Wa, const float* __restrict__ Wo,
    const float* __restrict__ W1, const float* __restrict__ W2,
    __hip_bfloat16* __restrict__ wbase) {
  __shared__ float tile[64][65];
  int blk = blockIdx.x;
  const float* W; __hip_bfloat16* Wt; int K, N;
  if (blk < 16)       { W = Wv;   Wt = wbase + 0;      K = 256;  N = 256; }
  else if (blk < 32)  { W = Woff; Wt = wbase + 65536;  K = 256;  N = 256;  blk -= 16; }
  else if (blk < 40)  { W = Wa;   Wt = wbase + 131072; K = 256;  N = 128;  blk -= 32; }
  else if (blk < 56)  { W = Wo;   Wt = wbase + 163840; K = 256;  N = 256;  blk -= 40; }
  else if (blk < 120) { W = W1;   Wt = wbase + 229376; K = 256;  N = 1024; blk -= 56; }
  else                { W = W2;   Wt = wbase + 491520; K = 1024; N = 256;  blk -= 120; }
  const int ntiles = N >> 6;
  const int kt = blk / ntiles, nt = blk % ntiles;
  const int c = threadIdx.x & 63, r0 = threadIdx.x >> 6;
#pragma unroll
  for (int i = 0; i < 16; ++i) {
    const int r = r0 + i * 4;
    tile[r][c] = W[(long)(kt * 64 + r) * N + nt * 64 + c];
  }
  __syncthreads();
#pragma unroll
  for (int i = 0; i < 16; ++i) {
    const int n = r0 + i * 4;
    Wt[(long)(nt * 64 + n) * K + kt * 64 + c] = __float2bfloat16(tile[c][n]);
  }
}

// ------------------------------------------------------------- MFMA GEMM 64x128
// Tile 64x128, BK=64, 256 thr (2x2 waves), XOR-swizzled LDS.
// MODE 2: bf16 out + ReLU. MODE 4: bf16 out.
template <int MODE>
__global__ __launch_bounds__(256) void gemm_bf16(
    const __hip_bfloat16* __restrict__ A, const __hip_bfloat16* __restrict__ Bt,
    const float* __restrict__ bias, const float* __restrict__ bias2, int bsplit,
    void* __restrict__ Cp, int M, int N, int K) {
  __shared__ short smA[64 * 64];    // 8KB
  __shared__ short smB[128 * 64];   // 16KB
  const int tid = threadIdx.x;
  const int lane = tid & 63;
  const int w = tid >> 6;
  const int wr = w >> 1, wc = w & 1;
  const long bm = (long)blockIdx.x * 64;
  const long bn = (long)blockIdx.y * 128;

  f32x4 acc[2][4];
#pragma unroll
  for (int i = 0; i < 2; ++i)
#pragma unroll
    for (int j = 0; j < 4; ++j) acc[i][j] = (f32x4)(0.f);

  const int srow = tid >> 3;
  const int su = (tid & 7) ^ (srow & 7);
  const __hip_bfloat16* Ag = A + (bm + srow) * (long)K + su * 8;
  const __hip_bfloat16* Bg = Bt + (bn + srow) * (long)K + su * 8;
  char* lA = (char*)smA + tid * 16;
  char* lB = (char*)smB + tid * 16;

  for (int k0 = 0; k0 < K; k0 += 64) {
    gload16(Ag,           lA);
    gload16(Ag + 32L * K, lA + 4096);
    gload16(Bg,           lB);
    gload16(Bg + 32L * K, lB + 4096);
    gload16(Bg + 64L * K, lB + 8192);
    gload16(Bg + 96L * K, lB + 12288);
    Ag += 64; Bg += 64;
    __syncthreads();
#pragma unroll
    for (int ks = 0; ks < 2; ++ks) {
      const int u = ks * 4 + (lane >> 4);
      short8 af[2], bf[4];
#pragma unroll
      for (int mi = 0; mi < 2; ++mi) {
        const int r = wr * 32 + (lane & 15) + mi * 16;
        af[mi] = *reinterpret_cast<const short8*>(
            (char*)smA + r * 128 + ((u ^ (r & 7)) * 16));
      }
#pragma unroll
      for (int ni = 0; ni < 4; ++ni) {
        const int r = wc * 64 + (lane & 15) + ni * 16;
        bf[ni] = *reinterpret_cast<const short8*>(
            (char*)smB + r * 128 + ((u ^ (r & 7)) * 16));
      }
#pragma unroll
      for (int mi = 0; mi < 2; ++mi)
#pragma unroll
        for (int ni = 0; ni < 4; ++ni)
          acc[mi][ni] = __builtin_amdgcn_mfma_f32_16x16x32_bf16(af[mi], bf[ni], acc[mi][ni], 0, 0, 0);
    }
    __syncthreads();
  }

  const int crow0 = wr * 32 + ((lane >> 4) << 2);
  const int ccol0 = wc * 64 + (lane & 15);
#pragma unroll
  for (int mi = 0; mi < 2; ++mi) {
#pragma unroll
    for (int ni = 0; ni < 4; ++ni) {
      const int col = bn + ccol0 + ni * 16;
      const float bs = (col < bsplit) ? bias[col] : bias2[col - bsplit];
#pragma unroll
      for (int r = 0; r < 4; ++r) {
        const long row = bm + crow0 + mi * 16 + r;
        float v = acc[mi][ni][r] + bs;
        if (MODE == 2) {
          ((__hip_bfloat16*)Cp)[row * N + col] = __float2bfloat16(fmaxf(v, 0.f));
        } else {
          ((__hip_bfloat16*)Cp)[row * N + col] = __float2bfloat16(v);
        }
      }
    }
  }
}

// ------------------------------------------------------------- value GEMM + q prep
// blocks < NVAL: val = src(f32) @ Wv^T + bv -> bf16 scatter [B][NH][S][DH]
// blocks >= NVAL: q = bf16(q_feat + q_pos), padded to MQ_P rows (memory-bound
// streaming; overlaps with the GEMM blocks' MFMA phase). No shared deps.
#define NVAL_ (MV_P / 64)   // 612
__global__ __launch_bounds__(256) void gemm_val(
    const float* __restrict__ A, const __hip_bfloat16* __restrict__ Bt,
    const float* __restrict__ bias, __hip_bfloat16* __restrict__ Cp, int Mreal,
    const float* __restrict__ qf, const float* __restrict__ qp,
    __hip_bfloat16* __restrict__ q_bf) {
  __shared__ short smA[64 * 64];    // 8KB
  __shared__ short smB[256 * 64];   // 32KB
  if (blockIdx.x >= NVAL_) {
    long idx = (long)(blockIdx.x - NVAL_) * 256 + threadIdx.x;
    int row = idx >> 5, c8 = (idx & 31) * 8;
    union { __hip_bfloat16 h[8]; uint4 u; } o;
    if (row < B_ * NQ_) {
      const float4 a0 = *reinterpret_cast<const float4*>(qf + (long)row * 256 + c8);
      const float4 a1 = *reinterpret_cast<const float4*>(qf + (long)row * 256 + c8 + 4);
      const float4 b0 = *reinterpret_cast<const float4*>(qp + (long)row * 256 + c8);
      const float4 b1 = *reinterpret_cast<const float4*>(qp + (long)row * 256 + c8 + 4);
      o.h[0] = __float2bfloat16(a0.x + b0.x); o.h[1] = __float2bfloat16(a0.y + b0.y);
      o.h[2] = __float2bfloat16(a0.z + b0.z); o.h[3] = __float2bfloat16(a0.w + b0.w);
      o.h[4] = __float2bfloat16(a1.x + b1.x); o.h[5] = __float2bfloat16(a1.y + b1.y);
      o.h[6] = __float2bfloat16(a1.z + b1.z); o.h[7] = __float2bfloat16(a1.w + b1.w);
    } else o.u = make_uint4(0, 0, 0, 0);
    if (row < MQ_P) *reinterpret_cast<uint4*>(q_bf + (long)row * 256 + c8) = o.u;
    return;
  }
  const int tid = threadIdx.x;
  const int lane = tid & 63;
  const int w = tid >> 6;
  const long bm = (long)blockIdx.x * 64;

  f32x4 acc[4][4];
#pragma unroll
  for (int i = 0; i < 4; ++i)
#pragma unroll
    for (int j = 0; j < 4; ++j) acc[i][j] = (f32x4)(0.f);

  const int ar = tid >> 2;
  const int au = (tid & 3) * 2;
  const bool arow_ok = (bm + ar) < Mreal;
  const float* Afp = A + (bm + ar) * 256L + au * 8;
  char* wA0 = (char*)smA + ar * 128 + ((au ^ (ar & 7)) * 16);
  char* wA1 = (char*)smA + ar * 128 + (((au + 1) ^ (ar & 7)) * 16);

  const int srow = tid >> 3;
  const int su = (tid & 7) ^ (srow & 7);
  const __hip_bfloat16* Bg = Bt + (long)srow * 256 + su * 8;
  char* lB = (char*)smB + tid * 16;

  for (int k0 = 0; k0 < 256; k0 += 64) {
#pragma unroll
    for (int j = 0; j < 8; ++j) gload16(Bg + 32L * j * 256, lB + 4096 * j);
    Bg += 64;
    float4 f0 = make_float4(0.f, 0.f, 0.f, 0.f), f1 = f0, f2 = f0, f3 = f0;
    if (arow_ok) {
      f0 = *reinterpret_cast<const float4*>(Afp + k0);
      f1 = *reinterpret_cast<const float4*>(Afp + k0 + 4);
      f2 = *reinterpret_cast<const float4*>(Afp + k0 + 8);
      f3 = *reinterpret_cast<const float4*>(Afp + k0 + 12);
    }
    union { __hip_bfloat16 h[8]; uint4 u; } c0, c1;
    c0.h[0] = __float2bfloat16(f0.x); c0.h[1] = __float2bfloat16(f0.y);
    c0.h[2] = __float2bfloat16(f0.z); c0.h[3] = __float2bfloat16(f0.w);
    c0.h[4] = __float2bfloat16(f1.x); c0.h[5] = __float2bfloat16(f1.y);
    c0.h[6] = __float2bfloat16(f1.z); c0.h[7] = __float2bfloat16(f1.w);
    c1.h[0] = __float2bfloat16(f2.x); c1.h[1] = __float2bfloat16(f2.y);
    c1.h[2] = __float2bfloat16(f2.z); c1.h[3] = __float2bfloat16(f2.w);
    c1.h[4] = __float2bfloat16(f3.x); c1.h[5] = __float2bfloat16(f3.y);
    c1.h[6] = __float2bfloat16(f3.z); c1.h[7] = __float2bfloat16(f3.w);
    *reinterpret_cast<uint4*>(wA0) = c0.u;
    *reinterpret_cast<uint4*>(wA1) = c1.u;
    __syncthreads();
#pragma unroll
    for (int ks = 0; ks < 2; ++ks) {
      const int u = ks * 4 + (lane >> 4);
      short8 af[4], bf[4];
#pragma unroll
      for (int mi = 0; mi < 4; ++mi) {
        const int r = (lane & 15) + mi * 16;
        af[mi] = *reinterpret_cast<const short8*>(
            (char*)smA + r * 128 + ((u ^ (r & 7)) * 16));
      }
#pragma unroll
      for (int ni = 0; ni < 4; ++ni) {
        const int r = w * 64 + ni * 16 + (lane & 15);
        bf[ni] = *reinterpret_cast<const short8*>(
            (char*)smB + r * 128 + ((u ^ (r & 7)) * 16));
      }
#pragma unroll
      for (int mi = 0; mi < 4; ++mi)
#pragma unroll
        for (int ni = 0; ni < 4; ++ni)
          acc[mi][ni] = __builtin_amdgcn_mfma_f32_16x16x32_bf16(af[mi], bf[ni], acc[mi][ni], 0, 0, 0);
    }
    __syncthreads();
  }

  const int crow0 = (lane >> 4) << 2;
  const int cl = lane & 15;
#pragma unroll
  for (int mi = 0; mi < 4; ++mi) {
#pragma unroll
    for (int ni = 0; ni < 4; ++ni) {
      const int col = w * 64 + ni * 16 + cl;
      const float bs = bias[col];
      const int h = col >> 5, dh = col & 31;
#pragma unroll
      for (int r = 0; r < 4; ++r) {
        const long row = bm + mi * 16 + crow0 + r;
        if (row < Mreal) {
          const int b = (row >= S_) ? 1 : 0;
          const long s = row - (long)b * S_;
          Cp[(((long)(b * 8 + h)) * S_ + s) * 32 + dh] =
              __float2bfloat16(acc[mi][ni][r] + bs);
        }
      }
    }
  }
}

// ------------------------------------------------------------- ms_deform
__global__ __launch_bounds__(256) void msdeform_kernel(
    const __hip_bfloat16* __restrict__ value, const __hip_bfloat16* __restrict__ oa,
    const float* __restrict__ q_ref, const float* __restrict__ vr,
    __hip_bfloat16* __restrict__ out) {
  const int t = blockIdx.x * 256 + threadIdx.x;
  const int tid7 = t & 127;
  const int dq = tid7 & 3;
  const int l = (tid7 >> 2) & 3;
  const int h = tid7 >> 4;
  const int lane = threadIdx.x & 63;
  const int grp = lane & ~3;
  const int bq = __builtin_amdgcn_readfirstlane(t >> 7);
  const int b = (bq >= NQ_) ? 1 : 0;

  const int W  = (l == 0) ? 160 : (l == 1) ? 80 : (l == 2) ? 40 : 20;
  const int H  = (l == 0) ? 92  : (l == 1) ? 46 : (l == 2) ? 23 : 12;
  const int S0 = (l == 0) ? 0 : (l == 1) ? 14720 : (l == 2) ? 18400 : 19320;

  const __hip_bfloat16* oabase = oa + (long)bq * 384;
  const uint2 mu = *reinterpret_cast<const uint2*>(oabase + 256 + h * 16 + l * 4);
  const float l0 = bflo(mu.x), l1 = bfhi(mu.x), l2 = bflo(mu.y), l3 = bfhi(mu.y);
  float mx = fmaxf(fmaxf(l0, l1), fmaxf(l2, l3));
  mx = fmaxf(mx, __shfl_xor(mx, 4, 64));
  mx = fmaxf(mx, __shfl_xor(mx, 8, 64));
  const float e0 = __expf(l0 - mx), e1 = __expf(l1 - mx);
  const float e2 = __expf(l2 - mx), e3 = __expf(l3 - mx);
  float sum = e0 + e1 + e2 + e3;
  sum += __shfl_xor(sum, 4, 64);
  sum += __shfl_xor(sum, 8, 64);
  const float inv = 1.f / sum;

  const uint4 ou = *reinterpret_cast<const uint4*>(oabase + h * 32 + l * 8);

  const float rx = q_ref[(long)bq * 2 + 0];
  const float ry = q_ref[(long)bq * 2 + 1];
  const float2 vv = *reinterpret_cast<const float2*>(vr + (b * 4 + l) * 2);
  const float refxW = rx * vv.x * W - 0.5f;
  const float refyH = ry * vv.y * H - 0.5f;
  const unsigned base32 = (unsigned)(((b * 8 + h) * S_ + S0) * 32 + dq * 8);

  const float eo = (dq & 2) ? ((dq & 1) ? e3 : e2) : ((dq & 1) ? e1 : e0);
  const float aw = eo * inv;
  const unsigned ox_u = (dq & 2) ? ((dq & 1) ? ou.w : ou.z)
                                 : ((dq & 1) ? ou.y : ou.x);

  unsigned spat[4]; float wt4[4];
  {
    const float x = refxW + bflo(ox_u);
    const float y = refyH + bfhi(ox_u);
    const float x0f = floorf(x), y0f = floorf(y);
    const float lx = x - x0f, ly = y - y0f;
    const int x0 = (int)x0f, y0 = (int)y0f;
    const int x1 = x0 + 1, y1 = y0 + 1;
    const float wx0 = ((unsigned)x0 < (unsigned)W) ? (1.f - lx) : 0.f;
    const float wx1 = ((unsigned)x1 < (unsigned)W) ? lx : 0.f;
    const float wy0 = ((unsigned)y0 < (unsigned)H) ? (1.f - ly) : 0.f;
    const float wy1 = ((unsigned)y1 < (unsigned)H) ? ly : 0.f;
    const int x0c = min(max(x0, 0), W - 1);
    const int x1c = min(max(x1, 0), W - 1);
    const int y0c = min(max(y0, 0), H - 1);
    const int y1c = min(max(y1, 0), H - 1);
    spat[0] = (unsigned)(y0c * W + x0c) * 32;
    spat[1] = (unsigned)(y0c * W + x1c) * 32;
    spat[2] = (unsigned)(y1c * W + x0c) * 32;
    spat[3] = (unsigned)(y1c * W + x1c) * 32;
    wt4[0] = aw * wx0 * wy0; wt4[1] = aw * wx1 * wy0;
    wt4[2] = aw * wx0 * wy1; wt4[3] = aw * wx1 * wy1;
  }

  unsigned offs[16]; float wts[16];
#pragma unroll
  for (int s = 0; s < 4; ++s) {
    const int src = grp + s;
#pragma unroll
    for (int c = 0; c < 4; ++c) {
      offs[s * 4 + c] = base32 + (unsigned)__shfl((int)spat[c], src, 64);
      wts[s * 4 + c] = __shfl(wt4[c], src, 64);
    }
  }

  uint4 d[16];
#pragma unroll
  for (int j = 0; j < 16; ++j)
    d[j] = *reinterpret_cast<const uint4*>(value + offs[j]);
  __builtin_amdgcn_sched_barrier(0);

  f32x2 acc2[4];
#pragma unroll
  for (int i = 0; i < 4; ++i) acc2[i] = (f32x2)(0.f);
#pragma unroll
  for (int j = 0; j < 16; ++j) {
    const f32x2 ww2 = (f32x2)(wts[j]);
    f32x2 v0, v1, v2, v3;
    v0.x = bflo(d[j].x); v0.y = bfhi_raw(d[j].x);
    v1.x = bflo(d[j].y); v1.y = bfhi_raw(d[j].y);
    v2.x = bflo(d[j].z); v2.y = bfhi_raw(d[j].z);
    v3.x = bflo(d[j].w); v3.y = bfhi_raw(d[j].w);
    acc2[0] += ww2 * v0;
    acc2[1] += ww2 * v1;
    acc2[2] += ww2 * v2;
    acc2[3] += ww2 * v3;
  }

  float accf[8] = {acc2[0].x, acc2[0].y, acc2[1].x, acc2[1].y,
                   acc2[2].x, acc2[2].y, acc2[3].x, acc2[3].y};
#pragma unroll
  for (int j = 0; j < 8; ++j) accf[j] += __shfl_xor(accf[j], 4, 64);
#pragma unroll
  for (int j = 0; j < 8; ++j) accf[j] += __shfl_xor(accf[j], 8, 64);

  if (l == 0) {
    union { __hip_bfloat16 hh[8]; uint4 u; } o0;
#pragma unroll
    for (int j = 0; j < 8; ++j) o0.hh[j] = __float2bfloat16(accf[j]);
    *reinterpret_cast<uint4*>(out + (long)bq * 256 + h * 32 + dq * 8) = o0.u;
  }
}

// ------------------------------------------------------------- residual+LN
template <bool RES_F32, bool OUT_F32>
__global__ __launch_bounds__(256) void add_ln2(
    const void* __restrict__ resv, const __hip_bfloat16* __restrict__ xin,
    const float* __restrict__ gamma, const float* __restrict__ beta,
    float* __restrict__ outF, __hip_bfloat16* __restrict__ outB, int nrows) {
  int row = blockIdx.x * 4 + (threadIdx.x >> 6);
  int lane = threadIdx.x & 63;
  if (row >= nrows) return;
  float rv[4];
  if (RES_F32) {
    const float4 r4 = *reinterpret_cast<const float4*>((const float*)resv + (long)row * 256 + lane * 4);
    rv[0] = r4.x; rv[1] = r4.y; rv[2] = r4.z; rv[3] = r4.w;
  } else {
    const uint2 r2 = *reinterpret_cast<const uint2*>((const __hip_bfloat16*)resv + (long)row * 256 + lane * 4);
    rv[0] = bflo(r2.x); rv[1] = bfhi(r2.x); rv[2] = bflo(r2.y); rv[3] = bfhi(r2.y);
  }
  const uint2 x2 = *reinterpret_cast<const uint2*>(xin + (long)row * 256 + lane * 4);
  float tv[4] = {rv[0] + bflo(x2.x), rv[1] + bfhi(x2.x),
                 rv[2] + bflo(x2.y), rv[3] + bfhi(x2.y)};
  float s = tv[0] + tv[1] + tv[2] + tv[3];
#pragma unroll
  for (int o = 32; o > 0; o >>= 1) s += __shfl_xor(s, o, 64);
  float mean = s * (1.f / 256.f);
  float vs = 0.f;
#pragma unroll
  for (int j = 0; j < 4; ++j) { float dd = tv[j] - mean; vs += dd * dd; }
#pragma unroll
  for (int o = 32; o > 0; o >>= 1) vs += __shfl_xor(vs, o, 64);
  float inv = rsqrtf(vs * (1.f / 256.f) + 1e-5f);
  const float4 g = *reinterpret_cast<const float4*>(gamma + lane * 4);
  const float4 be = *reinterpret_cast<const float4*>(beta + lane * 4);
  float o4[4];
  o4[0] = (tv[0] - mean) * inv * g.x + be.x;
  o4[1] = (tv[1] - mean) * inv * g.y + be.y;
  o4[2] = (tv[2] - mean) * inv * g.z + be.z;
  o4[3] = (tv[3] - mean) * inv * g.w + be.w;
  if (OUT_F32) {
    float4 of = {o4[0], o4[1], o4[2], o4[3]};
    *reinterpret_cast<float4*>(outF + (long)row * 256 + lane * 4) = of;
  } else {
    union { __hip_bfloat16 h[4]; uint2 u; } p;
    p.h[0] = __float2bfloat16(o4[0]); p.h[1] = __float2bfloat16(o4[1]);
    p.h[2] = __float2bfloat16(o4[2]); p.h[3] = __float2bfloat16(o4[3]);
    *reinterpret_cast<uint2*>(outB + (long)row * 256 + lane * 4) = p.u;
  }
}

// ------------------------------------------------------------- launch
extern "C" void kernel_launch(void* const* d_in, const int* in_sizes, int n_in,
                              void* d_out, int out_size, void* d_ws, size_t ws_size,
                              hipStream_t stream) {
  const float* src    = (const float*)d_in[0];
  const float* q_feat = (const float*)d_in[1];
  const float* q_pos  = (const float*)d_in[2];
  const float* q_ref  = (const float*)d_in[3];
  const float* vr     = (const float*)d_in[4];
  const float* Wv     = (const float*)d_in[5];
  const float* bv     = (const float*)d_in[6];
  const float* Woff   = (const float*)d_in[7];
  const float* boff   = (const float*)d_in[8];
  const float* Wa     = (const float*)d_in[9];
  const float* ba     = (const float*)d_in[10];
  const float* Wo     = (const float*)d_in[11];
  const float* bo     = (const float*)d_in[12];
  const float* g1     = (const float*)d_in[13];
  const float* be1    = (const float*)d_in[14];
  const float* W1     = (const float*)d_in[15];
  const float* bf1    = (const float*)d_in[16];
  const float* W2     = (const float*)d_in[17];
  const float* bf2    = (const float*)d_in[18];
  const float* g2     = (const float*)d_in[19];
  const float* be2    = (const float*)d_in[20];

  char* ws = (char*)d_ws;
  __hip_bfloat16* val_bf = (__hip_bfloat16*)(ws + 0);          // [..msdeform]
  __hip_bfloat16* q_bf   = (__hip_bfloat16*)(ws + 20029440);   // [..oa gemm]
  __hip_bfloat16* a_bf   = (__hip_bfloat16*)(ws + 0);          // [proj..ln1]
  __hip_bfloat16* h1_bf  = (__hip_bfloat16*)(ws + 0);          // [ffn1..ffn2]
  __hip_bfloat16* oa_bf  = (__hip_bfloat16*)(ws + 41943040);   // [..msdeform]
  __hip_bfloat16* f2_bf  = (__hip_bfloat16*)(ws + 41943040);   // [ffn2..ln2]
  __hip_bfloat16* ms_bf  = (__hip_bfloat16*)(ws + 57671680);   // [..proj]
  __hip_bfloat16* x_bf   = (__hip_bfloat16*)(ws + 68157440);   // [ln1..ln2]
  __hip_bfloat16* wts    = (__hip_bfloat16*)(ws + 78643200);
  float* outp = (float*)d_out;

  const int Mq = B_ * NQ_;   // 20000
  const int Mv = B_ * S_;    // 39120
  const int BIG = 1 << 30;

  // weight transpose only
  prep_w<<<184, 256, 0, stream>>>(Wv, Woff, Wa, Wo, W1, W2, wts);
  // value GEMM (612 blocks) + q prep (2560 blocks) fused — independent work
  gemm_val<<<NVAL_ + MQ_P * 32 / 256, 256, 0, stream>>>(src, wts + 0, bv, val_bf, Mv,
                                                        q_feat, q_pos, q_bf);
  gemm_bf16<4><<<dim3(MQ_P / 64, 3), 256, 0, stream>>>(q_bf, wts + 65536, boff, ba, 256, oa_bf, MQ_P, 384, 256);
  msdeform_kernel<<<(Mq * 128) / 256, 256, 0, stream>>>(val_bf, oa_bf, q_ref, vr, ms_bf);
  gemm_bf16<4><<<dim3(MQ_P / 64, 2), 256, 0, stream>>>(ms_bf, wts + 163840, bo, bo, BIG, a_bf, MQ_P, 256, 256);
  add_ln2<true, false><<<(Mq + 3) / 4, 256, 0, stream>>>(q_feat, a_bf, g1, be1, nullptr, x_bf, Mq);
  gemm_bf16<2><<<dim3(MQ_P / 64, 8), 256, 0, stream>>>(x_bf, wts + 229376, bf1, bf1, BIG, h1_bf, MQ_P, 1024, 256);
  gemm_bf16<4><<<dim3(MQ_P / 64, 2), 256, 0, stream>>>(h1_bf, wts + 491520, bf2, bf2, BIG, f2_bf, MQ_P, 256, 1024);
  add_ln2<false, true><<<(Mq + 3) / 4, 256, 0, stream>>>(x_bf, f2_bf, g2, be2, outp, nullptr, Mq);
}

// Round 16
// 144.555 us; speedup vs baseline: 1.0688x; 1.0155x over previous
//
#include <hip/hip_runtime.h>
#include <hip/hip_bf16.h>
#include <cstdint>

#define B_   2
#define NQ_  10000
#define C_   256
#define NH_  8
#define DH_  32
#define DFF_ 1024
#define S_   19560
#define MQ_P 20480   // 320*64 tiles; %8==0 -> stable row->XCD map
#define MV_P 39168   // 612*64

typedef __attribute__((ext_vector_type(8))) short short8;
typedef __attribute__((ext_vector_type(4))) float f32x4;
typedef __attribute__((ext_vector_type(2))) float f32x2;

__device__ __forceinline__ void gload16(const void* g, void* l) {
  __builtin_amdgcn_global_load_lds(
      (const __attribute__((address_space(1))) unsigned int*)g,
      (__attribute__((address_space(3))) unsigned int*)l, 16, 0, 0);
}

__device__ __forceinline__ float bflo(unsigned u) {
  union { unsigned u; float f; } c; c.u = u << 16; return c.f;
}
__device__ __forceinline__ float bfhi(unsigned u) {
  union { unsigned u; float f; } c; c.u = u & 0xffff0000u; return c.f;
}
__device__ __forceinline__ float bfhi_raw(unsigned u) {
  union { unsigned u; float f; } c; c.u = u; return c.f;
}

// ------------------------------------------------------------- weight transpose
__global__ __launch_bounds__(256) void prep_w(
    const float* __restrict__ Wv, const float* __restrict__ Woff,
    const float* __restrict__ Wa, const float* __restrict__ Wo,
    const float* __restrict__ W1, const float* __restrict__ W2,
    __hip_bfloat16* __restrict__ wbase) {
  __shared__ float tile[64][65];
  int blk = blockIdx.x;
  const float* W; __hip_bfloat16* Wt; int K, N;
  if (blk < 16)       { W = Wv;   Wt = wbase + 0;      K = 256;  N = 256; }
  else if (blk < 32)  { W = Woff; Wt = wbase + 65536;  K = 256;  N = 256;  blk -= 16; }
  else if (blk < 40)  { W = Wa;   Wt = wbase + 131072; K = 256;  N = 128;  blk -= 32; }
  else if (blk < 56)  { W = Wo;   Wt = wbase + 163840; K = 256;  N = 256;  blk -= 40; }
  else if (blk < 120) { W = W1;   Wt = wbase + 229376; K = 256;  N = 1024; blk -= 56; }
  else                { W = W2;   Wt = wbase + 491520; K = 1024; N = 256;  blk -= 120; }
  const int ntiles = N >> 6;
  const int kt = blk / ntiles, nt = blk % ntiles;
  const int c = threadIdx.x & 63, r0 = threadIdx.x >> 6;
#pragma unroll
  for (int i = 0; i < 16; ++i) {
    const int r = r0 + i * 4;
    tile[r][c] = W[(long)(kt * 64 + r) * N + nt * 64 + c];
  }
  __syncthreads();
#pragma unroll
  for (int i = 0; i < 16; ++i) {
    const int n = r0 + i * 4;
    Wt[(long)(nt * 64 + n) * K + kt * 64 + c] = __float2bfloat16(tile[c][n]);
  }
}

// ------------------------------------------------------------- MFMA GEMM 64x128
template <int MODE>
__global__ __launch_bounds__(256) void gemm_bf16(
    const __hip_bfloat16* __restrict__ A, const __hip_bfloat16* __restrict__ Bt,
    const float* __restrict__ bias, const float* __restrict__ bias2, int bsplit,
    void* __restrict__ Cp, int M, int N, int K) {
  __shared__ short smA[64 * 64];    // 8KB
  __shared__ short smB[128 * 64];   // 16KB
  const int tid = threadIdx.x;
  const int lane = tid & 63;
  const int w = tid >> 6;
  const int wr = w >> 1, wc = w & 1;
  const long bm = (long)blockIdx.x * 64;
  const long bn = (long)blockIdx.y * 128;

  f32x4 acc[2][4];
#pragma unroll
  for (int i = 0; i < 2; ++i)
#pragma unroll
    for (int j = 0; j < 4; ++j) acc[i][j] = (f32x4)(0.f);

  const int srow = tid >> 3;
  const int su = (tid & 7) ^ (srow & 7);
  const __hip_bfloat16* Ag = A + (bm + srow) * (long)K + su * 8;
  const __hip_bfloat16* Bg = Bt + (bn + srow) * (long)K + su * 8;
  char* lA = (char*)smA + tid * 16;
  char* lB = (char*)smB + tid * 16;

  for (int k0 = 0; k0 < K; k0 += 64) {
    gload16(Ag,           lA);
    gload16(Ag + 32L * K, lA + 4096);
    gload16(Bg,           lB);
    gload16(Bg + 32L * K, lB + 4096);
    gload16(Bg + 64L * K, lB + 8192);
    gload16(Bg + 96L * K, lB + 12288);
    Ag += 64; Bg += 64;
    __syncthreads();
#pragma unroll
    for (int ks = 0; ks < 2; ++ks) {
      const int u = ks * 4 + (lane >> 4);
      short8 af[2], bf[4];
#pragma unroll
      for (int mi = 0; mi < 2; ++mi) {
        const int r = wr * 32 + (lane & 15) + mi * 16;
        af[mi] = *reinterpret_cast<const short8*>(
            (char*)smA + r * 128 + ((u ^ (r & 7)) * 16));
      }
#pragma unroll
      for (int ni = 0; ni < 4; ++ni) {
        const int r = wc * 64 + (lane & 15) + ni * 16;
        bf[ni] = *reinterpret_cast<const short8*>(
            (char*)smB + r * 128 + ((u ^ (r & 7)) * 16));
      }
#pragma unroll
      for (int mi = 0; mi < 2; ++mi)
#pragma unroll
        for (int ni = 0; ni < 4; ++ni)
          acc[mi][ni] = __builtin_amdgcn_mfma_f32_16x16x32_bf16(af[mi], bf[ni], acc[mi][ni], 0, 0, 0);
    }
    __syncthreads();
  }

  const int crow0 = wr * 32 + ((lane >> 4) << 2);
  const int ccol0 = wc * 64 + (lane & 15);
#pragma unroll
  for (int mi = 0; mi < 2; ++mi) {
#pragma unroll
    for (int ni = 0; ni < 4; ++ni) {
      const int col = bn + ccol0 + ni * 16;
      const float bs = (col < bsplit) ? bias[col] : bias2[col - bsplit];
#pragma unroll
      for (int r = 0; r < 4; ++r) {
        const long row = bm + crow0 + mi * 16 + r;
        float v = acc[mi][ni][r] + bs;
        if (MODE == 2) {
          ((__hip_bfloat16*)Cp)[row * N + col] = __float2bfloat16(fmaxf(v, 0.f));
        } else {
          ((__hip_bfloat16*)Cp)[row * N + col] = __float2bfloat16(v);
        }
      }
    }
  }
}

// ------------------------------------------------------------- value GEMM + q prep
#define NVAL_ (MV_P / 64)   // 612
__global__ __launch_bounds__(256) void gemm_val(
    const float* __restrict__ A, const __hip_bfloat16* __restrict__ Bt,
    const float* __restrict__ bias, __hip_bfloat16* __restrict__ Cp, int Mreal,
    const float* __restrict__ qf, const float* __restrict__ qp,
    __hip_bfloat16* __restrict__ q_bf) {
  __shared__ short smA[64 * 64];    // 8KB
  __shared__ short smB[256 * 64];   // 32KB
  if (blockIdx.x >= NVAL_) {
    long idx = (long)(blockIdx.x - NVAL_) * 256 + threadIdx.x;
    int row = idx >> 5, c8 = (idx & 31) * 8;
    union { __hip_bfloat16 h[8]; uint4 u; } o;
    if (row < B_ * NQ_) {
      const float4 a0 = *reinterpret_cast<const float4*>(qf + (long)row * 256 + c8);
      const float4 a1 = *reinterpret_cast<const float4*>(qf + (long)row * 256 + c8 + 4);
      const float4 b0 = *reinterpret_cast<const float4*>(qp + (long)row * 256 + c8);
      const float4 b1 = *reinterpret_cast<const float4*>(qp + (long)row * 256 + c8 + 4);
      o.h[0] = __float2bfloat16(a0.x + b0.x); o.h[1] = __float2bfloat16(a0.y + b0.y);
      o.h[2] = __float2bfloat16(a0.z + b0.z); o.h[3] = __float2bfloat16(a0.w + b0.w);
      o.h[4] = __float2bfloat16(a1.x + b1.x); o.h[5] = __float2bfloat16(a1.y + b1.y);
      o.h[6] = __float2bfloat16(a1.z + b1.z); o.h[7] = __float2bfloat16(a1.w + b1.w);
    } else o.u = make_uint4(0, 0, 0, 0);
    if (row < MQ_P) *reinterpret_cast<uint4*>(q_bf + (long)row * 256 + c8) = o.u;
    return;
  }
  const int tid = threadIdx.x;
  const int lane = tid & 63;
  const int w = tid >> 6;
  const long bm = (long)blockIdx.x * 64;

  f32x4 acc[4][4];
#pragma unroll
  for (int i = 0; i < 4; ++i)
#pragma unroll
    for (int j = 0; j < 4; ++j) acc[i][j] = (f32x4)(0.f);

  const int ar = tid >> 2;
  const int au = (tid & 3) * 2;
  const bool arow_ok = (bm + ar) < Mreal;
  const float* Afp = A + (bm + ar) * 256L + au * 8;
  char* wA0 = (char*)smA + ar * 128 + ((au ^ (ar & 7)) * 16);
  char* wA1 = (char*)smA + ar * 128 + (((au + 1) ^ (ar & 7)) * 16);

  const int srow = tid >> 3;
  const int su = (tid & 7) ^ (srow & 7);
  const __hip_bfloat16* Bg = Bt + (long)srow * 256 + su * 8;
  char* lB = (char*)smB + tid * 16;

  for (int k0 = 0; k0 < 256; k0 += 64) {
#pragma unroll
    for (int j = 0; j < 8; ++j) gload16(Bg + 32L * j * 256, lB + 4096 * j);
    Bg += 64;
    float4 f0 = make_float4(0.f, 0.f, 0.f, 0.f), f1 = f0, f2 = f0, f3 = f0;
    if (arow_ok) {
      f0 = *reinterpret_cast<const float4*>(Afp + k0);
      f1 = *reinterpret_cast<const float4*>(Afp + k0 + 4);
      f2 = *reinterpret_cast<const float4*>(Afp + k0 + 8);
      f3 = *reinterpret_cast<const float4*>(Afp + k0 + 12);
    }
    union { __hip_bfloat16 h[8]; uint4 u; } c0, c1;
    c0.h[0] = __float2bfloat16(f0.x); c0.h[1] = __float2bfloat16(f0.y);
    c0.h[2] = __float2bfloat16(f0.z); c0.h[3] = __float2bfloat16(f0.w);
    c0.h[4] = __float2bfloat16(f1.x); c0.h[5] = __float2bfloat16(f1.y);
    c0.h[6] = __float2bfloat16(f1.z); c0.h[7] = __float2bfloat16(f1.w);
    c1.h[0] = __float2bfloat16(f2.x); c1.h[1] = __float2bfloat16(f2.y);
    c1.h[2] = __float2bfloat16(f2.z); c1.h[3] = __float2bfloat16(f2.w);
    c1.h[4] = __float2bfloat16(f3.x); c1.h[5] = __float2bfloat16(f3.y);
    c1.h[6] = __float2bfloat16(f3.z); c1.h[7] = __float2bfloat16(f3.w);
    *reinterpret_cast<uint4*>(wA0) = c0.u;
    *reinterpret_cast<uint4*>(wA1) = c1.u;
    __syncthreads();
#pragma unroll
    for (int ks = 0; ks < 2; ++ks) {
      const int u = ks * 4 + (lane >> 4);
      short8 af[4], bf[4];
#pragma unroll
      for (int mi = 0; mi < 4; ++mi) {
        const int r = (lane & 15) + mi * 16;
        af[mi] = *reinterpret_cast<const short8*>(
            (char*)smA + r * 128 + ((u ^ (r & 7)) * 16));
      }
#pragma unroll
      for (int ni = 0; ni < 4; ++ni) {
        const int r = w * 64 + ni * 16 + (lane & 15);
        bf[ni] = *reinterpret_cast<const short8*>(
            (char*)smB + r * 128 + ((u ^ (r & 7)) * 16));
      }
#pragma unroll
      for (int mi = 0; mi < 4; ++mi)
#pragma unroll
        for (int ni = 0; ni < 4; ++ni)
          acc[mi][ni] = __builtin_amdgcn_mfma_f32_16x16x32_bf16(af[mi], bf[ni], acc[mi][ni], 0, 0, 0);
    }
    __syncthreads();
  }

  const int crow0 = (lane >> 4) << 2;
  const int cl = lane & 15;
#pragma unroll
  for (int mi = 0; mi < 4; ++mi) {
#pragma unroll
    for (int ni = 0; ni < 4; ++ni) {
      const int col = w * 64 + ni * 16 + cl;
      const float bs = bias[col];
      const int h = col >> 5, dh = col & 31;
#pragma unroll
      for (int r = 0; r < 4; ++r) {
        const long row = bm + mi * 16 + crow0 + r;
        if (row < Mreal) {
          const int b = (row >= S_) ? 1 : 0;
          const long s = row - (long)b * S_;
          Cp[(((long)(b * 8 + h)) * S_ + s) * 32 + dh] =
              __float2bfloat16(acc[mi][ni][r] + bs);
        }
      }
    }
  }
}

// ------------------------------------------------------------- ms_deform
// Head-partitioned blocks for L2 locality: block = 16 queries x ONE (b,h)
// region; blk = qc*16 + (h*2+b) so blk%8 is constant per region -> all blocks
// of one region land on one XCD (empirical id%8), hot set/XCD ~5MB vs 20MB.
// Thread: tid = qi(4b,high) | l(2b) | dq(2b,low). 16-lane unit per query:
// dq coalesced 64B gathers; l reduced via shfl_xor(4,8) (in-unit).
__global__ __launch_bounds__(256) void msdeform_kernel(
    const __hip_bfloat16* __restrict__ value, const __hip_bfloat16* __restrict__ oa,
    const float* __restrict__ q_ref, const float* __restrict__ vr,
    __hip_bfloat16* __restrict__ out) {
  const int tid = threadIdx.x;
  const int dq = tid & 3;
  const int l = (tid >> 2) & 3;
  const int qi = tid >> 4;                       // 0..15
  const int reg = blockIdx.x & 15;               // h*2 + b
  const int h = reg >> 1;
  const int b = reg & 1;
  const int qc = blockIdx.x >> 4;                // 0..624
  const int bq = b * NQ_ + qc * 16 + qi;
  const int lane = tid & 63;
  const int grp = lane & ~3;

  const int W  = (l == 0) ? 160 : (l == 1) ? 80 : (l == 2) ? 40 : 20;
  const int H  = (l == 0) ? 92  : (l == 1) ? 46 : (l == 2) ? 23 : 12;
  const int S0 = (l == 0) ? 0 : (l == 1) ? 14720 : (l == 2) ? 18400 : 19320;

  const __hip_bfloat16* oabase = oa + (long)bq * 384;
  const uint2 mu = *reinterpret_cast<const uint2*>(oabase + 256 + h * 16 + l * 4);
  const float l0 = bflo(mu.x), l1 = bfhi(mu.x), l2 = bflo(mu.y), l3 = bfhi(mu.y);
  float mx = fmaxf(fmaxf(l0, l1), fmaxf(l2, l3));
  mx = fmaxf(mx, __shfl_xor(mx, 4, 64));
  mx = fmaxf(mx, __shfl_xor(mx, 8, 64));
  const float e0 = __expf(l0 - mx), e1 = __expf(l1 - mx);
  const float e2 = __expf(l2 - mx), e3 = __expf(l3 - mx);
  float sum = e0 + e1 + e2 + e3;
  sum += __shfl_xor(sum, 4, 64);
  sum += __shfl_xor(sum, 8, 64);
  const float inv = 1.f / sum;

  const uint4 ou = *reinterpret_cast<const uint4*>(oabase + h * 32 + l * 8);

  const float rx = q_ref[(long)bq * 2 + 0];
  const float ry = q_ref[(long)bq * 2 + 1];
  const float2 vv = *reinterpret_cast<const float2*>(vr + (b * 4 + l) * 2);
  const float refxW = rx * vv.x * W - 0.5f;
  const float refyH = ry * vv.y * H - 0.5f;
  const unsigned base32 = (unsigned)(((b * 8 + h) * S_ + S0) * 32 + dq * 8);

  const float eo = (dq & 2) ? ((dq & 1) ? e3 : e2) : ((dq & 1) ? e1 : e0);
  const float aw = eo * inv;
  const unsigned ox_u = (dq & 2) ? ((dq & 1) ? ou.w : ou.z)
                                 : ((dq & 1) ? ou.y : ou.x);

  unsigned spat[4]; float wt4[4];
  {
    const float x = refxW + bflo(ox_u);
    const float y = refyH + bfhi(ox_u);
    const float x0f = floorf(x), y0f = floorf(y);
    const float lx = x - x0f, ly = y - y0f;
    const int x0 = (int)x0f, y0 = (int)y0f;
    const int x1 = x0 + 1, y1 = y0 + 1;
    const float wx0 = ((unsigned)x0 < (unsigned)W) ? (1.f - lx) : 0.f;
    const float wx1 = ((unsigned)x1 < (unsigned)W) ? lx : 0.f;
    const float wy0 = ((unsigned)y0 < (unsigned)H) ? (1.f - ly) : 0.f;
    const float wy1 = ((unsigned)y1 < (unsigned)H) ? ly : 0.f;
    const int x0c = min(max(x0, 0), W - 1);
    const int x1c = min(max(x1, 0), W - 1);
    const int y0c = min(max(y0, 0), H - 1);
    const int y1c = min(max(y1, 0), H - 1);
    spat[0] = (unsigned)(y0c * W + x0c) * 32;
    spat[1] = (unsigned)(y0c * W + x1c) * 32;
    spat[2] = (unsigned)(y1c * W + x0c) * 32;
    spat[3] = (unsigned)(y1c * W + x1c) * 32;
    wt4[0] = aw * wx0 * wy0; wt4[1] = aw * wx1 * wy0;
    wt4[2] = aw * wx0 * wy1; wt4[3] = aw * wx1 * wy1;
  }

  unsigned offs[16]; float wts[16];
#pragma unroll
  for (int s = 0; s < 4; ++s) {
    const int src = grp + s;
#pragma unroll
    for (int c = 0; c < 4; ++c) {
      offs[s * 4 + c] = base32 + (unsigned)__shfl((int)spat[c], src, 64);
      wts[s * 4 + c] = __shfl(wt4[c], src, 64);
    }
  }

  uint4 d[16];
#pragma unroll
  for (int j = 0; j < 16; ++j)
    d[j] = *reinterpret_cast<const uint4*>(value + offs[j]);
  __builtin_amdgcn_sched_barrier(0);

  f32x2 acc2[4];
#pragma unroll
  for (int i = 0; i < 4; ++i) acc2[i] = (f32x2)(0.f);
#pragma unroll
  for (int j = 0; j < 16; ++j) {
    const f32x2 ww2 = (f32x2)(wts[j]);
    f32x2 v0, v1, v2, v3;
    v0.x = bflo(d[j].x); v0.y = bfhi_raw(d[j].x);
    v1.x = bflo(d[j].y); v1.y = bfhi_raw(d[j].y);
    v2.x = bflo(d[j].z); v2.y = bfhi_raw(d[j].z);
    v3.x = bflo(d[j].w); v3.y = bfhi_raw(d[j].w);
    acc2[0] += ww2 * v0;
    acc2[1] += ww2 * v1;
    acc2[2] += ww2 * v2;
    acc2[3] += ww2 * v3;
  }

  float accf[8] = {acc2[0].x, acc2[0].y, acc2[1].x, acc2[1].y,
                   acc2[2].x, acc2[2].y, acc2[3].x, acc2[3].y};
#pragma unroll
  for (int j = 0; j < 8; ++j) accf[j] += __shfl_xor(accf[j], 4, 64);
#pragma unroll
  for (int j = 0; j < 8; ++j) accf[j] += __shfl_xor(accf[j], 8, 64);

  if (l == 0) {
    union { __hip_bfloat16 hh[8]; uint4 u; } o0;
#pragma unroll
    for (int j = 0; j < 8; ++j) o0.hh[j] = __float2bfloat16(accf[j]);
    *reinterpret_cast<uint4*>(out + (long)bq * 256 + h * 32 + dq * 8) = o0.u;
  }
}

// ------------------------------------------------------------- residual+LN
template <bool RES_F32, bool OUT_F32>
__global__ __launch_bounds__(256) void add_ln2(
    const void* __restrict__ resv, const __hip_bfloat16* __restrict__ xin,
    const float* __restrict__ gamma, const float* __restrict__ beta,
    float* __restrict__ outF, __hip_bfloat16* __restrict__ outB, int nrows) {
  int row = blockIdx.x * 4 + (threadIdx.x >> 6);
  int lane = threadIdx.x & 63;
  if (row >= nrows) return;
  float rv[4];
  if (RES_F32) {
    const float4 r4 = *reinterpret_cast<const float4*>((const float*)resv + (long)row * 256 + lane * 4);
    rv[0] = r4.x; rv[1] = r4.y; rv[2] = r4.z; rv[3] = r4.w;
  } else {
    const uint2 r2 = *reinterpret_cast<const uint2*>((const __hip_bfloat16*)resv + (long)row * 256 + lane * 4);
    rv[0] = bflo(r2.x); rv[1] = bfhi(r2.x); rv[2] = bflo(r2.y); rv[3] = bfhi(r2.y);
  }
  const uint2 x2 = *reinterpret_cast<const uint2*>(xin + (long)row * 256 + lane * 4);
  float tv[4] = {rv[0] + bflo(x2.x), rv[1] + bfhi(x2.x),
                 rv[2] + bflo(x2.y), rv[3] + bfhi(x2.y)};
  float s = tv[0] + tv[1] + tv[2] + tv[3];
#pragma unroll
  for (int o = 32; o > 0; o >>= 1) s += __shfl_xor(s, o, 64);
  float mean = s * (1.f / 256.f);
  float vs = 0.f;
#pragma unroll
  for (int j = 0; j < 4; ++j) { float dd = tv[j] - mean; vs += dd * dd; }
#pragma unroll
  for (int o = 32; o > 0; o >>= 1) vs += __shfl_xor(vs, o, 64);
  float inv = rsqrtf(vs * (1.f / 256.f) + 1e-5f);
  const float4 g = *reinterpret_cast<const float4*>(gamma + lane * 4);
  const float4 be = *reinterpret_cast<const float4*>(beta + lane * 4);
  float o4[4];
  o4[0] = (tv[0] - mean) * inv * g.x + be.x;
  o4[1] = (tv[1] - mean) * inv * g.y + be.y;
  o4[2] = (tv[2] - mean) * inv * g.z + be.z;
  o4[3] = (tv[3] - mean) * inv * g.w + be.w;
  if (OUT_F32) {
    float4 of = {o4[0], o4[1], o4[2], o4[3]};
    *reinterpret_cast<float4*>(outF + (long)row * 256 + lane * 4) = of;
  } else {
    union { __hip_bfloat16 h[4]; uint2 u; } p;
    p.h[0] = __float2bfloat16(o4[0]); p.h[1] = __float2bfloat16(o4[1]);
    p.h[2] = __float2bfloat16(o4[2]); p.h[3] = __float2bfloat16(o4[3]);
    *reinterpret_cast<uint2*>(outB + (long)row * 256 + lane * 4) = p.u;
  }
}

// ------------------------------------------------------------- launch
extern "C" void kernel_launch(void* const* d_in, const int* in_sizes, int n_in,
                              void* d_out, int out_size, void* d_ws, size_t ws_size,
                              hipStream_t stream) {
  const float* src    = (const float*)d_in[0];
  const float* q_feat = (const float*)d_in[1];
  const float* q_pos  = (const float*)d_in[2];
  const float* q_ref  = (const float*)d_in[3];
  const float* vr     = (const float*)d_in[4];
  const float* Wv     = (const float*)d_in[5];
  const float* bv     = (const float*)d_in[6];
  const float* Woff   = (const float*)d_in[7];
  const float* boff   = (const float*)d_in[8];
  const float* Wa     = (const float*)d_in[9];
  const float* ba     = (const float*)d_in[10];
  const float* Wo     = (const float*)d_in[11];
  const float* bo     = (const float*)d_in[12];
  const float* g1     = (const float*)d_in[13];
  const float* be1    = (const float*)d_in[14];
  const float* W1     = (const float*)d_in[15];
  const float* bf1    = (const float*)d_in[16];
  const float* W2     = (const float*)d_in[17];
  const float* bf2    = (const float*)d_in[18];
  const float* g2     = (const float*)d_in[19];
  const float* be2    = (const float*)d_in[20];

  char* ws = (char*)d_ws;
  __hip_bfloat16* val_bf = (__hip_bfloat16*)(ws + 0);          // [..msdeform]
  __hip_bfloat16* q_bf   = (__hip_bfloat16*)(ws + 20029440);   // [..oa gemm]
  __hip_bfloat16* a_bf   = (__hip_bfloat16*)(ws + 0);          // [proj..ln1]
  __hip_bfloat16* h1_bf  = (__hip_bfloat16*)(ws + 0);          // [ffn1..ffn2]
  __hip_bfloat16* oa_bf  = (__hip_bfloat16*)(ws + 41943040);   // [..msdeform]
  __hip_bfloat16* f2_bf  = (__hip_bfloat16*)(ws + 41943040);   // [ffn2..ln2]
  __hip_bfloat16* ms_bf  = (__hip_bfloat16*)(ws + 57671680);   // [..proj]
  __hip_bfloat16* x_bf   = (__hip_bfloat16*)(ws + 68157440);   // [ln1..ln2]
  __hip_bfloat16* wts    = (__hip_bfloat16*)(ws + 78643200);
  float* outp = (float*)d_out;

  const int Mq = B_ * NQ_;   // 20000
  const int Mv = B_ * S_;    // 39120
  const int BIG = 1 << 30;

  prep_w<<<184, 256, 0, stream>>>(Wv, Woff, Wa, Wo, W1, W2, wts);
  gemm_val<<<NVAL_ + MQ_P * 32 / 256, 256, 0, stream>>>(src, wts + 0, bv, val_bf, Mv,
                                                        q_feat, q_pos, q_bf);
  gemm_bf16<4><<<dim3(MQ_P / 64, 3), 256, 0, stream>>>(q_bf, wts + 65536, boff, ba, 256, oa_bf, MQ_P, 384, 256);
  // head-partitioned: 625 q-chunks x 16 (b,h) regions
  msdeform_kernel<<<(NQ_ / 16) * 16, 256, 0, stream>>>(val_bf, oa_bf, q_ref, vr, ms_bf);
  gemm_bf16<4><<<dim3(MQ_P / 64, 2), 256, 0, stream>>>(ms_bf, wts + 163840, bo, bo, BIG, a_bf, MQ_P, 256, 256);
  add_ln2<true, false><<<(Mq + 3) / 4, 256, 0, stream>>>(q_feat, a_bf, g1, be1, nullptr, x_bf, Mq);
  gemm_bf16<2><<<dim3(MQ_P / 64, 8), 256, 0, stream>>>(x_bf, wts + 229376, bf1, bf1, BIG, h1_bf, MQ_P, 1024, 256);
  gemm_bf16<4><<<dim3(MQ_P / 64, 2), 256, 0, stream>>>(h1_bf, wts + 491520, bf2, bf2, BIG, f2_bf, MQ_P, 256, 1024);
  add_ln2<false, true><<<(Mq + 3) / 4, 256, 0, stream>>>(x_bf, f2_bf, g2, be2, outp, nullptr, Mq);
}